// Round 1
// baseline (1580.287 us; speedup 1.0000x reference)
//
#include <hip/hip_runtime.h>
#include <math.h>

#define T_SEQ 2048
#define C_DIM 1024
#define NH    16
#define HD    64
#define HIN   4
#define DI    32
#define SINKN 4
#define KMINV 32
#define KMAXV 1024

__device__ __forceinline__ float sigf(float x) { return 1.f / (1.f + expf(-x)); }

// ---------------- generic f32 GEMM tile: C = A @ B^T ----------------
// A: M x 1024 row-major, B: N x 1024 row-major, tile 128x128, BK=16, 8x8 micro
__device__ __forceinline__ void gemm_tile_body(
    const float* __restrict__ A, const float* __restrict__ B, float* __restrict__ Cm,
    int m0, int n0, int N)
{
    __shared__ float As[16][132];
    __shared__ float Bs[16][132];
    const int K = C_DIM;
    const int tid = threadIdx.x;
    const int tx = tid & 15, ty = tid >> 4;

    float acc[8][8];
#pragma unroll
    for (int i = 0; i < 8; ++i)
#pragma unroll
        for (int j = 0; j < 8; ++j) acc[i][j] = 0.f;

    const int sr = tid >> 1;
    const int sk = (tid & 1) * 8;
    const float* Ap = A + (size_t)(m0 + sr) * K + sk;
    const float* Bp = B + (size_t)(n0 + sr) * K + sk;

    for (int k0 = 0; k0 < K; k0 += 16) {
        float4 a0 = *(const float4*)(Ap + k0);
        float4 a1 = *(const float4*)(Ap + k0 + 4);
        float4 b0 = *(const float4*)(Bp + k0);
        float4 b1 = *(const float4*)(Bp + k0 + 4);
        __syncthreads();
        As[sk + 0][sr] = a0.x; As[sk + 1][sr] = a0.y; As[sk + 2][sr] = a0.z; As[sk + 3][sr] = a0.w;
        As[sk + 4][sr] = a1.x; As[sk + 5][sr] = a1.y; As[sk + 6][sr] = a1.z; As[sk + 7][sr] = a1.w;
        Bs[sk + 0][sr] = b0.x; Bs[sk + 1][sr] = b0.y; Bs[sk + 2][sr] = b0.z; Bs[sk + 3][sr] = b0.w;
        Bs[sk + 4][sr] = b1.x; Bs[sk + 5][sr] = b1.y; Bs[sk + 6][sr] = b1.z; Bs[sk + 7][sr] = b1.w;
        __syncthreads();
#pragma unroll
        for (int kk = 0; kk < 16; ++kk) {
            float4 aA = *(const float4*)&As[kk][ty * 4];
            float4 aB = *(const float4*)&As[kk][64 + ty * 4];
            float4 bA = *(const float4*)&Bs[kk][tx * 4];
            float4 bB = *(const float4*)&Bs[kk][64 + tx * 4];
            float am[8] = {aA.x, aA.y, aA.z, aA.w, aB.x, aB.y, aB.z, aB.w};
            float bn[8] = {bA.x, bA.y, bA.z, bA.w, bB.x, bB.y, bB.z, bB.w};
#pragma unroll
            for (int i = 0; i < 8; ++i)
#pragma unroll
                for (int j = 0; j < 8; ++j) acc[i][j] = fmaf(am[i], bn[j], acc[i][j]);
        }
    }

#pragma unroll
    for (int ih = 0; ih < 2; ++ih)
#pragma unroll
        for (int i = 0; i < 4; ++i) {
            const int row = m0 + ih * 64 + ty * 4 + i;
            float* cp = Cm + (size_t)row * N + n0;
            float4 v0 = make_float4(acc[ih*4+i][0], acc[ih*4+i][1], acc[ih*4+i][2], acc[ih*4+i][3]);
            float4 v1 = make_float4(acc[ih*4+i][4], acc[ih*4+i][5], acc[ih*4+i][6], acc[ih*4+i][7]);
            *(float4*)(cp + tx * 4) = v0;
            *(float4*)(cp + 64 + tx * 4) = v1;
        }
}

// fused projections: q,k,v,gv,go (N=1024 each) + qI,kI (N=128 each)
__global__ __launch_bounds__(256) void gemm_proj_kernel(
    const float* __restrict__ x,
    const float* __restrict__ Wq, const float* __restrict__ Wk, const float* __restrict__ Wv,
    const float* __restrict__ Wgv, const float* __restrict__ Wgo,
    const float* __restrict__ WIq, const float* __restrict__ WIk,
    float* __restrict__ qlin, float* __restrict__ klin, float* __restrict__ vlin,
    float* __restrict__ gvlin, float* __restrict__ golin,
    float* __restrict__ qI, float* __restrict__ kI)
{
    const int cb = blockIdx.x;
    const float* B; float* Out; int N; int n0;
    if (cb < 40) {
        const int which = cb >> 3; n0 = (cb & 7) * 128; N = C_DIM;
        switch (which) {
            case 0:  B = Wq;  Out = qlin;  break;
            case 1:  B = Wk;  Out = klin;  break;
            case 2:  B = Wv;  Out = vlin;  break;
            case 3:  B = Wgv; Out = gvlin; break;
            default: B = Wgo; Out = golin; break;
        }
    } else if (cb == 40) { B = WIq; Out = qI; N = HIN * DI; n0 = 0; }
    else                 { B = WIk; Out = kI; N = HIN * DI; n0 = 0; }
    gemm_tile_body(x, B, Out, blockIdx.y * 128, n0, N);
}

__global__ __launch_bounds__(256) void gemm_single_kernel(
    const float* __restrict__ A, const float* __restrict__ B, float* __restrict__ Cm, int N)
{
    gemm_tile_body(A, B, Cm, blockIdx.y * 128, blockIdx.x * 128, N);
}

// w = sigmoid(x @ W_Iw^T), one thread per (t, hi)
__global__ void proj_w_kernel(const float* __restrict__ x, const float* __restrict__ WIw,
                              float* __restrict__ wsig)
{
    const int idx = blockIdx.x * 256 + threadIdx.x;   // t*4 + hi
    const int t = idx >> 2, hi = idx & 3;
    const float4* xr = (const float4*)(x + (size_t)t * C_DIM);
    const float4* wr = (const float4*)(WIw + (size_t)hi * C_DIM);
    float s = 0.f;
    for (int i = 0; i < C_DIM / 4; ++i) {
        float4 a = xr[i], b = wr[i];
        s += a.x * b.x + a.y * b.y + a.z * b.z + a.w * b.w;
    }
    wsig[idx] = sigf(s);
}

// kIt[hi][d][k] = kI[k][hi*32+d]  (coalesced indexer dot products)
__global__ void transpose_kI_kernel(const float* __restrict__ kI, float* __restrict__ kIt)
{
    const int idx = blockIdx.x * 256 + threadIdx.x;  // (hi*32+d)*2048 + k
    const int k = idx & (T_SEQ - 1);
    const int d = (idx >> 11) & 31;
    const int hi = idx >> 16;
    kIt[idx] = kI[(size_t)k * (HIN * DI) + hi * DI + d];
}

__global__ void rope_table_kernel(float* __restrict__ cost, float* __restrict__ sint)
{
    const int idx = blockIdx.x * 256 + threadIdx.x;   // t*32 + i
    const int t = idx >> 5, i = idx & 31;
    const int j = (2 * i) & 31;
    const double invd = pow(10000.0, -(double)j / 32.0);
    const float invf = (float)invd;                    // mimic f32 inv_freq
    const float f = (float)t * invf;                   // f32 phase like reference
    cost[idx] = (float)cos((double)f);
    sint[idx] = (float)sin((double)f);
}

// RoPE on q,k; v = v * sigmoid(gv); outputs in (H, T, 64) layout
__global__ void rope_v_kernel(
    const float* __restrict__ qlin, const float* __restrict__ klin,
    const float* __restrict__ vlin, const float* __restrict__ gvlin,
    const float* __restrict__ cost, const float* __restrict__ sint,
    float* __restrict__ Q, float* __restrict__ K, float* __restrict__ V)
{
    const int idx = blockIdx.x * 256 + threadIdx.x;   // (t*16+h)*32 + i
    const int i = idx & 31;
    const int h = (idx >> 5) & 15;
    const int t = idx >> 9;
    const float cv = cost[t * 32 + i], sv = sint[t * 32 + i];
    const size_t src = (size_t)t * C_DIM + h * HD + 2 * i;
    const float2 q2 = *(const float2*)(qlin + src);
    const float2 k2 = *(const float2*)(klin + src);
    const float2 v2 = *(const float2*)(vlin + src);
    const float2 g2 = *(const float2*)(gvlin + src);
    const size_t dst = ((size_t)h * T_SEQ + t) * HD;
    Q[dst + i]      = q2.x * cv - q2.y * sv;
    Q[dst + 32 + i] = q2.x * sv + q2.y * cv;
    K[dst + i]      = k2.x * cv - k2.y * sv;
    K[dst + 32 + i] = k2.x * sv + k2.y * cv;
    float2 vo;
    vo.x = v2.x * sigf(g2.x);
    vo.y = v2.y * sigf(g2.y);
    *(float2*)(V + dst + 2 * i) = vo;
}

// per (q, indexer) row: importance, var->k_t (4 heads), stable sort -> selection bitmask
__global__ __launch_bounds__(256) void indexer_kernel(
    const float* __restrict__ qI, const float* __restrict__ kIt,
    const float* __restrict__ wsig,
    const float* __restrict__ gate_bias, const float* __restrict__ head_bias,
    unsigned* __restrict__ sel)
{
    const int q = blockIdx.x;
    const int hi = blockIdx.y;
    const int tid = threadIdx.x;

    __shared__ float qv[DI];
    __shared__ unsigned long long keys[T_SEQ];
    __shared__ double red[256];
    __shared__ unsigned selb[256];   // [4 heads][64 words]
    __shared__ int kts[4];

    if (tid < DI) qv[tid] = qI[(size_t)q * (HIN * DI) + hi * DI + tid];
    __syncthreads();

    const float wr = wsig[q * HIN + hi];
    const float gb = gate_bias[hi];

    double dsum = 0.0, dsq = 0.0;
    for (int kb = 0; kb < T_SEQ; kb += 256) {
        const int k = kb + tid;
        unsigned vb;
        if (k <= q) {
            float dot = 0.f;
#pragma unroll
            for (int d = 0; d < DI; ++d)
                dot = fmaf(qv[d], kIt[(size_t)(hi * DI + d) * T_SEQ + k], dot);
            const float g = sigf(dot + gb);
            const float imp = wr * g;      // base importance (head scale applied via var only)
            dsum += (double)imp;
            dsq  += (double)imp * (double)imp;
            vb = (k < SINKN) ? 0x7F800000u : __float_as_uint(imp);
        } else {
            vb = (k < SINKN) ? 0x7F800000u : 0u;  // sinks +inf even past causal; -inf -> 0
        }
        keys[k] = ((unsigned long long)vb << 16) | (unsigned long long)(T_SEQ - 1 - k);
    }

    red[tid] = dsum;
    __syncthreads();
    for (int s = 128; s > 0; s >>= 1) { if (tid < s) red[tid] += red[tid + s]; __syncthreads(); }
    const double sumv = red[0];
    __syncthreads();
    red[tid] = dsq;
    __syncthreads();
    for (int s = 128; s > 0; s >>= 1) { if (tid < s) red[tid] += red[tid + s]; __syncthreads(); }
    const double sqv = red[0];

    if (tid < 4) {
        const int h = hi * 4 + tid;
        const float sh = sigf(head_bias[h]);
        const double mean = sumv / (double)T_SEQ;
        double var = sqv / (double)T_SEQ - mean * mean;
        if (var < 0.0) var = 0.0;
        const double varh = var * (double)sh * (double)sh;
        int kt = (int)floor(512.0 * varh);
        if (kt < KMINV) kt = KMINV;
        if (kt > KMAXV) kt = KMAXV;
        kts[tid] = kt;
    }
    selb[tid] = 0u;
    __syncthreads();

    // bitonic sort, descending on (value_bits, reverse index) -> stable top-k order
    for (int size = 2; size <= T_SEQ; size <<= 1) {
        for (int stride = size >> 1; stride > 0; stride >>= 1) {
#pragma unroll 1
            for (int i = tid; i < T_SEQ / 2; i += 256) {
                const int lo = ((i & ~(stride - 1)) << 1) | (i & (stride - 1));
                const int hi2 = lo + stride;
                const unsigned long long a = keys[lo];
                const unsigned long long b = keys[hi2];
                const bool desc = ((lo & size) == 0);
                if (desc ? (a < b) : (a > b)) { keys[lo] = b; keys[hi2] = a; }
            }
            __syncthreads();
        }
    }

    int ktmax = kts[0];
    ktmax = kts[1] > ktmax ? kts[1] : ktmax;
    ktmax = kts[2] > ktmax ? kts[2] : ktmax;
    ktmax = kts[3] > ktmax ? kts[3] : ktmax;

    for (int pos = tid; pos < KMAXV; pos += 256) {
        if (pos < ktmax) {
            const int k = (T_SEQ - 1) - (int)(keys[pos] & 0xFFFFull);
            const unsigned bit = 1u << (k & 31);
#pragma unroll
            for (int j = 0; j < 4; ++j)
                if (pos < kts[j]) atomicOr(&selb[j * 64 + (k >> 5)], bit);
        }
    }
    __syncthreads();

    const int j = tid >> 6, w = tid & 63;
    sel[((size_t)(hi * 4 + j) * T_SEQ + q) * 64 + w] = selb[tid];
}

// flash-style masked attention; 64 q-rows per block, 4 threads per row
__global__ __launch_bounds__(256) void attn_kernel(
    const float* __restrict__ Q, const float* __restrict__ K, const float* __restrict__ V,
    const unsigned* __restrict__ sel, float* __restrict__ o_flat)
{
    const int h = blockIdx.y;
    const int q0 = blockIdx.x * 64;
    const int tid = threadIdx.x;
    const int r = tid >> 2;
    const int c = tid & 3;
    const int q = q0 + r;

    __shared__ float Ks[64][HD];
    __shared__ float Vs[64][HD];
    __shared__ unsigned sels[64][2];

    float qreg[16];
    {
        const float* qp = Q + ((size_t)h * T_SEQ + q) * HD + c * 16;
#pragma unroll
        for (int d4 = 0; d4 < 4; ++d4) {
            float4 t4 = *(const float4*)(qp + d4 * 4);
            qreg[d4*4+0] = t4.x; qreg[d4*4+1] = t4.y; qreg[d4*4+2] = t4.z; qreg[d4*4+3] = t4.w;
        }
    }
    float o[16];
#pragma unroll
    for (int d = 0; d < 16; ++d) o[d] = 0.f;
    float m = -INFINITY, l = 0.f;

    const int ntile = (q0 >> 6) + 1;
    for (int t = 0; t < ntile; ++t) {
        const int k0 = t * 64;
        __syncthreads();
        {
            const int rr = tid >> 2;
            const int cc = (tid & 3) * 16;
            const float* kp = K + ((size_t)h * T_SEQ + k0 + rr) * HD + cc;
            const float* vp = V + ((size_t)h * T_SEQ + k0 + rr) * HD + cc;
#pragma unroll
            for (int e = 0; e < 16; e += 4) {
                *(float4*)&Ks[rr][cc + e] = *(const float4*)(kp + e);
                *(float4*)&Vs[rr][cc + e] = *(const float4*)(vp + e);
            }
            if (tid < 128)
                sels[tid >> 1][tid & 1] =
                    sel[((size_t)h * T_SEQ + q0 + (tid >> 1)) * 64 + (k0 >> 5) + (tid & 1)];
        }
        __syncthreads();

#pragma unroll 1
        for (int ch = 0; ch < 4; ++ch) {
            float sc[16];
#pragma unroll
            for (int jj = 0; jj < 16; ++jj) {
                const int kk = ch * 16 + jj;
                const float4* kr4 = (const float4*)&Ks[kk][c * 16];
                float p = 0.f;
#pragma unroll
                for (int d4 = 0; d4 < 4; ++d4) {
                    float4 kv = kr4[d4];
                    p = fmaf(qreg[d4*4+0], kv.x, p);
                    p = fmaf(qreg[d4*4+1], kv.y, p);
                    p = fmaf(qreg[d4*4+2], kv.z, p);
                    p = fmaf(qreg[d4*4+3], kv.w, p);
                }
                p += __shfl_xor(p, 1);
                p += __shfl_xor(p, 2);
                const int kg = k0 + kk;
                const bool ok = (kg <= q) && ((sels[r][kk >> 5] >> (kg & 31)) & 1u);
                sc[jj] = ok ? p * 0.125f : -INFINITY;
            }
            float cm = sc[0];
#pragma unroll
            for (int jj = 1; jj < 16; ++jj) cm = fmaxf(cm, sc[jj]);
            const float mn = fmaxf(m, cm);
            if (mn == -INFINITY) continue;
            const float alpha = expf(m - mn);
            float pj[16];
            float ls = 0.f;
#pragma unroll
            for (int jj = 0; jj < 16; ++jj) { pj[jj] = expf(sc[jj] - mn); ls += pj[jj]; }
            l = l * alpha + ls;
#pragma unroll
            for (int d = 0; d < 16; ++d) o[d] *= alpha;
#pragma unroll
            for (int jj = 0; jj < 16; ++jj) {
                const float pv = pj[jj];
                const float4* vr4 = (const float4*)&Vs[ch * 16 + jj][c * 16];
#pragma unroll
                for (int d4 = 0; d4 < 4; ++d4) {
                    float4 vv = vr4[d4];
                    o[d4*4+0] = fmaf(pv, vv.x, o[d4*4+0]);
                    o[d4*4+1] = fmaf(pv, vv.y, o[d4*4+1]);
                    o[d4*4+2] = fmaf(pv, vv.z, o[d4*4+2]);
                    o[d4*4+3] = fmaf(pv, vv.w, o[d4*4+3]);
                }
            }
            m = mn;
        }
    }
    const float invl = 1.f / l;
    float* op = o_flat + (size_t)q * C_DIM + h * HD + c * 16;
#pragma unroll
    for (int d4 = 0; d4 < 4; ++d4) {
        float4 v4 = make_float4(o[d4*4+0]*invl, o[d4*4+1]*invl, o[d4*4+2]*invl, o[d4*4+3]*invl);
        *(float4*)(op + d4 * 4) = v4;
    }
}

__global__ void gate_o_kernel(const float* __restrict__ o_flat, const float* __restrict__ golin,
                              float* __restrict__ og)
{
    const int idx = blockIdx.x * 256 + threadIdx.x;
    og[idx] = o_flat[idx] * sigf(golin[idx]);
}

extern "C" void kernel_launch(void* const* d_in, const int* in_sizes, int n_in,
                              void* d_out, int out_size, void* d_ws, size_t ws_size,
                              hipStream_t stream)
{
    const float* x   = (const float*)d_in[0];
    const float* WIq = (const float*)d_in[1];
    const float* WIk = (const float*)d_in[2];
    const float* WIw = (const float*)d_in[3];
    const float* gb  = (const float*)d_in[4];
    const float* hib = (const float*)d_in[5];
    const float* Wq  = (const float*)d_in[6];
    const float* Wk  = (const float*)d_in[7];
    const float* Wv  = (const float*)d_in[8];
    const float* Wgv = (const float*)d_in[9];
    const float* Wgo = (const float*)d_in[10];
    const float* Wo  = (const float*)d_in[11];
    float* out = (float*)d_out;

    char* ws = (char*)d_ws;
    const size_t MB = 1024 * 1024;
    float*    qI    = (float*)(ws + 0 * MB);            // 1 MB
    float*    kI    = (float*)(ws + 1 * MB);            // 1 MB
    float*    kIt   = (float*)(ws + 2 * MB);            // 1 MB
    float*    wsig  = (float*)(ws + 3 * MB);            // 32 KB
    float*    cost  = (float*)(ws + 3 * MB + 512 * 1024);  // 256 KB
    float*    sint  = (float*)(ws + 3 * MB + 768 * 1024);  // 256 KB
    unsigned* sel   = (unsigned*)(ws + 4 * MB);         // 8 MB
    float*    Q     = (float*)(ws + 12 * MB);           // 8 MB
    float*    K     = (float*)(ws + 20 * MB);           // 8 MB
    float*    V     = (float*)(ws + 28 * MB);           // 8 MB
    float*    qlin  = (float*)(ws + 36 * MB);           // 8 MB
    float*    klin  = (float*)(ws + 44 * MB);           // 8 MB
    float*    vlin  = (float*)(ws + 52 * MB);           // 8 MB
    float*    gvlin = (float*)(ws + 60 * MB);           // 8 MB
    float*    golin = (float*)(ws + 68 * MB);           // 8 MB -> 76 MB total
    float*    o_flat = qlin;   // reuse (dead after rope)
    float*    og     = klin;   // reuse (dead after rope)

    gemm_proj_kernel<<<dim3(42, 16), 256, 0, stream>>>(
        x, Wq, Wk, Wv, Wgv, Wgo, WIq, WIk,
        qlin, klin, vlin, gvlin, golin, qI, kI);
    proj_w_kernel<<<dim3(32), 256, 0, stream>>>(x, WIw, wsig);
    transpose_kI_kernel<<<dim3(1024), 256, 0, stream>>>(kI, kIt);
    rope_table_kernel<<<dim3(256), 256, 0, stream>>>(cost, sint);
    rope_v_kernel<<<dim3(4096), 256, 0, stream>>>(qlin, klin, vlin, gvlin, cost, sint, Q, K, V);
    indexer_kernel<<<dim3(2048, 4), 256, 0, stream>>>(qI, kIt, wsig, gb, hib, sel);
    attn_kernel<<<dim3(32, 16), 256, 0, stream>>>(Q, K, V, sel, o_flat);
    gate_o_kernel<<<dim3(8192), 256, 0, stream>>>(o_flat, golin, og);
    gemm_single_kernel<<<dim3(8, 16), 256, 0, stream>>>(og, Wo, out, C_DIM);
}

// Round 2
// 1105.304 us; speedup vs baseline: 1.4297x; 1.4297x over previous
//
#include <hip/hip_runtime.h>
#include <math.h>

#define T_SEQ 2048
#define C_DIM 1024
#define NH    16
#define HD    64
#define HIN   4
#define DI    32
#define SINKN 4
#define KMINV 32
#define KMAXV 1024

__device__ __forceinline__ float sigf(float x) { return 1.f / (1.f + expf(-x)); }

// ---------------- generic f32 GEMM tile: C = A @ B^T ----------------
__device__ __forceinline__ void gemm_tile_body(
    const float* __restrict__ A, const float* __restrict__ B, float* __restrict__ Cm,
    int m0, int n0, int N)
{
    __shared__ float As[16][132];
    __shared__ float Bs[16][132];
    const int K = C_DIM;
    const int tid = threadIdx.x;
    const int tx = tid & 15, ty = tid >> 4;

    float acc[8][8];
#pragma unroll
    for (int i = 0; i < 8; ++i)
#pragma unroll
        for (int j = 0; j < 8; ++j) acc[i][j] = 0.f;

    const int sr = tid >> 1;
    const int sk = (tid & 1) * 8;
    const float* Ap = A + (size_t)(m0 + sr) * K + sk;
    const float* Bp = B + (size_t)(n0 + sr) * K + sk;

    for (int k0 = 0; k0 < K; k0 += 16) {
        float4 a0 = *(const float4*)(Ap + k0);
        float4 a1 = *(const float4*)(Ap + k0 + 4);
        float4 b0 = *(const float4*)(Bp + k0);
        float4 b1 = *(const float4*)(Bp + k0 + 4);
        __syncthreads();
        As[sk + 0][sr] = a0.x; As[sk + 1][sr] = a0.y; As[sk + 2][sr] = a0.z; As[sk + 3][sr] = a0.w;
        As[sk + 4][sr] = a1.x; As[sk + 5][sr] = a1.y; As[sk + 6][sr] = a1.z; As[sk + 7][sr] = a1.w;
        Bs[sk + 0][sr] = b0.x; Bs[sk + 1][sr] = b0.y; Bs[sk + 2][sr] = b0.z; Bs[sk + 3][sr] = b0.w;
        Bs[sk + 4][sr] = b1.x; Bs[sk + 5][sr] = b1.y; Bs[sk + 6][sr] = b1.z; Bs[sk + 7][sr] = b1.w;
        __syncthreads();
#pragma unroll
        for (int kk = 0; kk < 16; ++kk) {
            float4 aA = *(const float4*)&As[kk][ty * 4];
            float4 aB = *(const float4*)&As[kk][64 + ty * 4];
            float4 bA = *(const float4*)&Bs[kk][tx * 4];
            float4 bB = *(const float4*)&Bs[kk][64 + tx * 4];
            float am[8] = {aA.x, aA.y, aA.z, aA.w, aB.x, aB.y, aB.z, aB.w};
            float bn[8] = {bA.x, bA.y, bA.z, bA.w, bB.x, bB.y, bB.z, bB.w};
#pragma unroll
            for (int i = 0; i < 8; ++i)
#pragma unroll
                for (int j = 0; j < 8; ++j) acc[i][j] = fmaf(am[i], bn[j], acc[i][j]);
        }
    }

#pragma unroll
    for (int ih = 0; ih < 2; ++ih)
#pragma unroll
        for (int i = 0; i < 4; ++i) {
            const int row = m0 + ih * 64 + ty * 4 + i;
            float* cp = Cm + (size_t)row * N + n0;
            float4 v0 = make_float4(acc[ih*4+i][0], acc[ih*4+i][1], acc[ih*4+i][2], acc[ih*4+i][3]);
            float4 v1 = make_float4(acc[ih*4+i][4], acc[ih*4+i][5], acc[ih*4+i][6], acc[ih*4+i][7]);
            *(float4*)(cp + tx * 4) = v0;
            *(float4*)(cp + 64 + tx * 4) = v1;
        }
}

__global__ __launch_bounds__(256) void gemm_proj_kernel(
    const float* __restrict__ x,
    const float* __restrict__ Wq, const float* __restrict__ Wk, const float* __restrict__ Wv,
    const float* __restrict__ Wgv, const float* __restrict__ Wgo,
    const float* __restrict__ WIq, const float* __restrict__ WIk,
    float* __restrict__ qlin, float* __restrict__ klin, float* __restrict__ vlin,
    float* __restrict__ gvlin, float* __restrict__ golin,
    float* __restrict__ qI, float* __restrict__ kI)
{
    const int cb = blockIdx.x;
    const float* B; float* Out; int N; int n0;
    if (cb < 40) {
        const int which = cb >> 3; n0 = (cb & 7) * 128; N = C_DIM;
        switch (which) {
            case 0:  B = Wq;  Out = qlin;  break;
            case 1:  B = Wk;  Out = klin;  break;
            case 2:  B = Wv;  Out = vlin;  break;
            case 3:  B = Wgv; Out = gvlin; break;
            default: B = Wgo; Out = golin; break;
        }
    } else if (cb == 40) { B = WIq; Out = qI; N = HIN * DI; n0 = 0; }
    else                 { B = WIk; Out = kI; N = HIN * DI; n0 = 0; }
    gemm_tile_body(x, B, Out, blockIdx.y * 128, n0, N);
}

__global__ __launch_bounds__(256) void gemm_single_kernel(
    const float* __restrict__ A, const float* __restrict__ B, float* __restrict__ Cm, int N)
{
    gemm_tile_body(A, B, Cm, blockIdx.y * 128, blockIdx.x * 128, N);
}

__global__ void proj_w_kernel(const float* __restrict__ x, const float* __restrict__ WIw,
                              float* __restrict__ wsig)
{
    const int idx = blockIdx.x * 256 + threadIdx.x;   // t*4 + hi
    const int t = idx >> 2, hi = idx & 3;
    const float4* xr = (const float4*)(x + (size_t)t * C_DIM);
    const float4* wr = (const float4*)(WIw + (size_t)hi * C_DIM);
    float s = 0.f;
    for (int i = 0; i < C_DIM / 4; ++i) {
        float4 a = xr[i], b = wr[i];
        s += a.x * b.x + a.y * b.y + a.z * b.z + a.w * b.w;
    }
    wsig[idx] = sigf(s);
}

__global__ void transpose_kI_kernel(const float* __restrict__ kI, float* __restrict__ kIt)
{
    const int idx = blockIdx.x * 256 + threadIdx.x;  // (hi*32+d)*2048 + k
    const int k = idx & (T_SEQ - 1);
    const int d = (idx >> 11) & 31;
    const int hi = idx >> 16;
    kIt[idx] = kI[(size_t)k * (HIN * DI) + hi * DI + d];
}

__global__ void rope_table_kernel(float* __restrict__ cost, float* __restrict__ sint)
{
    const int idx = blockIdx.x * 256 + threadIdx.x;   // t*32 + i
    const int t = idx >> 5, i = idx & 31;
    const int j = (2 * i) & 31;
    const double invd = pow(10000.0, -(double)j / 32.0);
    const float invf = (float)invd;
    const float f = (float)t * invf;
    cost[idx] = (float)cos((double)f);
    sint[idx] = (float)sin((double)f);
}

__global__ void rope_v_kernel(
    const float* __restrict__ qlin, const float* __restrict__ klin,
    const float* __restrict__ vlin, const float* __restrict__ gvlin,
    const float* __restrict__ cost, const float* __restrict__ sint,
    float* __restrict__ Q, float* __restrict__ K, float* __restrict__ V)
{
    const int idx = blockIdx.x * 256 + threadIdx.x;   // (t*16+h)*32 + i
    const int i = idx & 31;
    const int h = (idx >> 5) & 15;
    const int t = idx >> 9;
    const float cv = cost[t * 32 + i], sv = sint[t * 32 + i];
    const size_t src = (size_t)t * C_DIM + h * HD + 2 * i;
    const float2 q2 = *(const float2*)(qlin + src);
    const float2 k2 = *(const float2*)(klin + src);
    const float2 v2 = *(const float2*)(vlin + src);
    const float2 g2 = *(const float2*)(gvlin + src);
    const size_t dst = ((size_t)h * T_SEQ + t) * HD;
    Q[dst + i]      = q2.x * cv - q2.y * sv;
    Q[dst + 32 + i] = q2.x * sv + q2.y * cv;
    K[dst + i]      = k2.x * cv - k2.y * sv;
    K[dst + 32 + i] = k2.x * sv + k2.y * cv;
    float2 vo;
    vo.x = v2.x * sigf(g2.x);
    vo.y = v2.y * sigf(g2.y);
    *(float2*)(V + dst + 2 * i) = vo;
}

// per (q, indexer) row: importance, var->k_t (4 heads), stable sort -> sorted index list
__global__ __launch_bounds__(256) void indexer_kernel(
    const float* __restrict__ qI, const float* __restrict__ kIt,
    const float* __restrict__ wsig,
    const float* __restrict__ gate_bias, const float* __restrict__ head_bias,
    unsigned short* __restrict__ sidxg, int* __restrict__ ktsg)
{
    const int q = blockIdx.x;
    const int hi = blockIdx.y;
    const int tid = threadIdx.x;

    __shared__ float qv[DI];
    __shared__ unsigned long long keys[T_SEQ];
    __shared__ double red[256];
    __shared__ int kts[4];

    if (tid < DI) qv[tid] = qI[(size_t)q * (HIN * DI) + hi * DI + tid];
    __syncthreads();

    const float wr = wsig[q * HIN + hi];
    const float gb = gate_bias[hi];

    double dsum = 0.0, dsq = 0.0;
    for (int kb = 0; kb < T_SEQ; kb += 256) {
        const int k = kb + tid;
        unsigned vb;
        if (k <= q) {
            float dot = 0.f;
#pragma unroll
            for (int d = 0; d < DI; ++d)
                dot = fmaf(qv[d], kIt[(size_t)(hi * DI + d) * T_SEQ + k], dot);
            const float g = sigf(dot + gb);
            const float imp = wr * g;
            dsum += (double)imp;
            dsq  += (double)imp * (double)imp;
            vb = (k < SINKN) ? 0x7F800000u : __float_as_uint(imp);
        } else {
            vb = (k < SINKN) ? 0x7F800000u : 0u;
        }
        keys[k] = ((unsigned long long)vb << 16) | (unsigned long long)(T_SEQ - 1 - k);
    }

    red[tid] = dsum;
    __syncthreads();
    for (int s = 128; s > 0; s >>= 1) { if (tid < s) red[tid] += red[tid + s]; __syncthreads(); }
    const double sumv = red[0];
    __syncthreads();
    red[tid] = dsq;
    __syncthreads();
    for (int s = 128; s > 0; s >>= 1) { if (tid < s) red[tid] += red[tid + s]; __syncthreads(); }
    const double sqv = red[0];

    if (tid < 4) {
        const int h = hi * 4 + tid;
        const float sh = sigf(head_bias[h]);
        const double mean = sumv / (double)T_SEQ;
        double var = sqv / (double)T_SEQ - mean * mean;
        if (var < 0.0) var = 0.0;
        const double varh = var * (double)sh * (double)sh;
        int kt = (int)floor(512.0 * varh);
        if (kt < KMINV) kt = KMINV;
        if (kt > KMAXV) kt = KMAXV;
        kts[tid] = kt;
    }
    __syncthreads();

    // bitonic sort, descending on (value_bits, reverse index) -> stable top-k order
    for (int size = 2; size <= T_SEQ; size <<= 1) {
        for (int stride = size >> 1; stride > 0; stride >>= 1) {
#pragma unroll 1
            for (int i = tid; i < T_SEQ / 2; i += 256) {
                const int lo = ((i & ~(stride - 1)) << 1) | (i & (stride - 1));
                const int hi2 = lo + stride;
                const unsigned long long a = keys[lo];
                const unsigned long long b = keys[hi2];
                const bool desc = ((lo & size) == 0);
                if (desc ? (a < b) : (a > b)) { keys[lo] = b; keys[hi2] = a; }
            }
            __syncthreads();
        }
    }

    int ktmax = kts[0];
    ktmax = kts[1] > ktmax ? kts[1] : ktmax;
    ktmax = kts[2] > ktmax ? kts[2] : ktmax;
    ktmax = kts[3] > ktmax ? kts[3] : ktmax;
    const int nw = (ktmax + 63) & ~63;

    const size_t hq = (size_t)hi * T_SEQ + q;
    if (tid < 4) ktsg[hq * 4 + tid] = kts[tid];
    for (int pos = tid; pos < nw; pos += 256)
        sidxg[hq * KMAXV + pos] =
            (unsigned short)((T_SEQ - 1) - (int)(keys[pos] & 0xFFFFull));
}

// sparse gather attention: one wave per (head, query)
__global__ __launch_bounds__(256) void attn_sparse_kernel(
    const float* __restrict__ Q, const float* __restrict__ K, const float* __restrict__ V,
    const unsigned short* __restrict__ sidx, const int* __restrict__ kts,
    float* __restrict__ o_flat)
{
    const int h  = blockIdx.y;
    const int hi = h >> 2, hj = h & 3;
    const int wv = threadIdx.x >> 6;
    const int lane = threadIdx.x & 63;
    const int q = blockIdx.x * 4 + wv;

    const size_t hq = (size_t)hi * T_SEQ + q;
    const int kt = kts[hq * 4 + hj];
    const int nv = min(kt, q + 1);   // sorted list: causal entries are a prefix

    const float qd = Q[((size_t)h * T_SEQ + q) * HD + lane];  // lane = dim
    const unsigned short* sp = sidx + hq * KMAXV;
    const float* Kh = K + (size_t)h * T_SEQ * HD;
    const float* Vh = V + (size_t)h * T_SEQ * HD;

    float m = -INFINITY, l = 0.f, o = 0.f;

    for (int base = 0; base < nv; base += 64) {
        const int nk = min(64, nv - base);
        const int idxv = (lane < nk) ? (int)sp[base + lane] : 0;

        // lane-per-key dot (all lanes execute; invalid lanes read K[0], masked after)
        const float4* kr = (const float4*)(Kh + (size_t)idxv * HD);
        float acc = 0.f;
#pragma unroll
        for (int d4 = 0; d4 < 16; ++d4) {
            float4 kv = kr[d4];
            acc = fmaf(__shfl(qd, d4 * 4 + 0), kv.x, acc);
            acc = fmaf(__shfl(qd, d4 * 4 + 1), kv.y, acc);
            acc = fmaf(__shfl(qd, d4 * 4 + 2), kv.z, acc);
            acc = fmaf(__shfl(qd, d4 * 4 + 3), kv.w, acc);
        }
        float s = (lane < nk && idxv <= q) ? acc * 0.125f : -INFINITY;

        float cm = s;
#pragma unroll
        for (int off = 32; off > 0; off >>= 1) cm = fmaxf(cm, __shfl_xor(cm, off));
        const float mn = fmaxf(m, cm);
        if (mn > -INFINITY) {
            const float alpha = expf(m - mn);
            const float p = expf(s - mn);
            float ls = p;
#pragma unroll
            for (int off = 32; off > 0; off >>= 1) ls += __shfl_xor(ls, off);
            l = l * alpha + ls;
            o = o * alpha;
            // dim-parallel PV: lane = dim, coalesced V rows
            for (int k = 0; k < nk; ++k) {
                const float pk = __shfl(p, k);
                const int iv = __shfl(idxv, k);
                o = fmaf(pk, Vh[(size_t)iv * HD + lane], o);
            }
            m = mn;
        }
    }
    const float invl = 1.f / l;
    o_flat[(size_t)q * C_DIM + h * HD + lane] = o * invl;
}

__global__ void gate_o_kernel(const float* __restrict__ o_flat, const float* __restrict__ golin,
                              float* __restrict__ og)
{
    const int idx = blockIdx.x * 256 + threadIdx.x;
    og[idx] = o_flat[idx] * sigf(golin[idx]);
}

extern "C" void kernel_launch(void* const* d_in, const int* in_sizes, int n_in,
                              void* d_out, int out_size, void* d_ws, size_t ws_size,
                              hipStream_t stream)
{
    const float* x   = (const float*)d_in[0];
    const float* WIq = (const float*)d_in[1];
    const float* WIk = (const float*)d_in[2];
    const float* WIw = (const float*)d_in[3];
    const float* gb  = (const float*)d_in[4];
    const float* hib = (const float*)d_in[5];
    const float* Wq  = (const float*)d_in[6];
    const float* Wk  = (const float*)d_in[7];
    const float* Wv  = (const float*)d_in[8];
    const float* Wgv = (const float*)d_in[9];
    const float* Wgo = (const float*)d_in[10];
    const float* Wo  = (const float*)d_in[11];
    float* out = (float*)d_out;

    char* ws = (char*)d_ws;
    const size_t MB = 1024 * 1024;
    float*    qI    = (float*)(ws + 0 * MB);                 // 1 MB
    float*    kI    = (float*)(ws + 1 * MB);                 // 1 MB
    float*    kIt   = (float*)(ws + 2 * MB);                 // 1 MB
    float*    wsig  = (float*)(ws + 3 * MB);                 // 32 KB
    int*      ktsg  = (int*)(ws + 3 * MB + 64 * 1024);       // 128 KB
    float*    cost  = (float*)(ws + 3 * MB + 512 * 1024);    // 256 KB
    float*    sint  = (float*)(ws + 3 * MB + 768 * 1024);    // 256 KB
    float*    Q     = (float*)(ws + 4 * MB);                 // 8 MB
    float*    K     = (float*)(ws + 12 * MB);                // 8 MB
    float*    V     = (float*)(ws + 20 * MB);                // 8 MB
    float*    qlin  = (float*)(ws + 28 * MB);                // 8 MB
    float*    klin  = (float*)(ws + 36 * MB);                // 8 MB
    float*    vlin  = (float*)(ws + 44 * MB);                // 8 MB
    float*    gvlin = (float*)(ws + 52 * MB);                // 8 MB
    float*    golin = (float*)(ws + 60 * MB);                // 8 MB -> 68 MB total
    // overlays (dead-after-rope regions):
    unsigned short* sidx = (unsigned short*)(ws + 44 * MB);  // 16 MB over vlin+gvlin
    float*    o_flat = qlin;   // dead after rope_v
    float*    og     = klin;   // dead after rope_v

    gemm_proj_kernel<<<dim3(42, 16), 256, 0, stream>>>(
        x, Wq, Wk, Wv, Wgv, Wgo, WIq, WIk,
        qlin, klin, vlin, gvlin, golin, qI, kI);
    proj_w_kernel<<<dim3(32), 256, 0, stream>>>(x, WIw, wsig);
    transpose_kI_kernel<<<dim3(1024), 256, 0, stream>>>(kI, kIt);
    rope_table_kernel<<<dim3(256), 256, 0, stream>>>(cost, sint);
    rope_v_kernel<<<dim3(4096), 256, 0, stream>>>(qlin, klin, vlin, gvlin, cost, sint, Q, K, V);
    indexer_kernel<<<dim3(2048, 4), 256, 0, stream>>>(qI, kIt, wsig, gb, hib, sidx, ktsg);
    attn_sparse_kernel<<<dim3(512, 16), 256, 0, stream>>>(Q, K, V, sidx, ktsg, o_flat);
    gate_o_kernel<<<dim3(8192), 256, 0, stream>>>(o_flat, golin, og);
    gemm_single_kernel<<<dim3(8, 16), 256, 0, stream>>>(og, Wo, out, C_DIM);
}

// Round 3
// 721.317 us; speedup vs baseline: 2.1908x; 1.5323x over previous
//
#include <hip/hip_runtime.h>
#include <math.h>

#define T_SEQ 2048
#define C_DIM 1024
#define NH    16
#define HD    64
#define HIN   4
#define DI    32
#define SINKN 4
#define KMINV 32
#define KMAXV 1024

__device__ __forceinline__ float sigf(float x) { return 1.f / (1.f + expf(-x)); }

// ---------------- generic f32 GEMM tile: C = A @ B^T ----------------
__device__ __forceinline__ void gemm_tile_body(
    const float* __restrict__ A, const float* __restrict__ B, float* __restrict__ Cm,
    int m0, int n0, int N)
{
    __shared__ float As[16][132];
    __shared__ float Bs[16][132];
    const int K = C_DIM;
    const int tid = threadIdx.x;
    const int tx = tid & 15, ty = tid >> 4;

    float acc[8][8];
#pragma unroll
    for (int i = 0; i < 8; ++i)
#pragma unroll
        for (int j = 0; j < 8; ++j) acc[i][j] = 0.f;

    const int sr = tid >> 1;
    const int sk = (tid & 1) * 8;
    const float* Ap = A + (size_t)(m0 + sr) * K + sk;
    const float* Bp = B + (size_t)(n0 + sr) * K + sk;

    for (int k0 = 0; k0 < K; k0 += 16) {
        float4 a0 = *(const float4*)(Ap + k0);
        float4 a1 = *(const float4*)(Ap + k0 + 4);
        float4 b0 = *(const float4*)(Bp + k0);
        float4 b1 = *(const float4*)(Bp + k0 + 4);
        __syncthreads();
        As[sk + 0][sr] = a0.x; As[sk + 1][sr] = a0.y; As[sk + 2][sr] = a0.z; As[sk + 3][sr] = a0.w;
        As[sk + 4][sr] = a1.x; As[sk + 5][sr] = a1.y; As[sk + 6][sr] = a1.z; As[sk + 7][sr] = a1.w;
        Bs[sk + 0][sr] = b0.x; Bs[sk + 1][sr] = b0.y; Bs[sk + 2][sr] = b0.z; Bs[sk + 3][sr] = b0.w;
        Bs[sk + 4][sr] = b1.x; Bs[sk + 5][sr] = b1.y; Bs[sk + 6][sr] = b1.z; Bs[sk + 7][sr] = b1.w;
        __syncthreads();
#pragma unroll
        for (int kk = 0; kk < 16; ++kk) {
            float4 aA = *(const float4*)&As[kk][ty * 4];
            float4 aB = *(const float4*)&As[kk][64 + ty * 4];
            float4 bA = *(const float4*)&Bs[kk][tx * 4];
            float4 bB = *(const float4*)&Bs[kk][64 + tx * 4];
            float am[8] = {aA.x, aA.y, aA.z, aA.w, aB.x, aB.y, aB.z, aB.w};
            float bn[8] = {bA.x, bA.y, bA.z, bA.w, bB.x, bB.y, bB.z, bB.w};
#pragma unroll
            for (int i = 0; i < 8; ++i)
#pragma unroll
                for (int j = 0; j < 8; ++j) acc[i][j] = fmaf(am[i], bn[j], acc[i][j]);
        }
    }

#pragma unroll
    for (int ih = 0; ih < 2; ++ih)
#pragma unroll
        for (int i = 0; i < 4; ++i) {
            const int row = m0 + ih * 64 + ty * 4 + i;
            float* cp = Cm + (size_t)row * N + n0;
            float4 v0 = make_float4(acc[ih*4+i][0], acc[ih*4+i][1], acc[ih*4+i][2], acc[ih*4+i][3]);
            float4 v1 = make_float4(acc[ih*4+i][4], acc[ih*4+i][5], acc[ih*4+i][6], acc[ih*4+i][7]);
            *(float4*)(cp + tx * 4) = v0;
            *(float4*)(cp + 64 + tx * 4) = v1;
        }
}

__global__ __launch_bounds__(256) void gemm_proj_kernel(
    const float* __restrict__ x,
    const float* __restrict__ Wq, const float* __restrict__ Wk, const float* __restrict__ Wv,
    const float* __restrict__ Wgv, const float* __restrict__ Wgo,
    const float* __restrict__ WIq, const float* __restrict__ WIk,
    float* __restrict__ qlin, float* __restrict__ klin, float* __restrict__ vlin,
    float* __restrict__ gvlin, float* __restrict__ golin,
    float* __restrict__ qI, float* __restrict__ kI)
{
    const int cb = blockIdx.x;
    const float* B; float* Out; int N; int n0;
    if (cb < 40) {
        const int which = cb >> 3; n0 = (cb & 7) * 128; N = C_DIM;
        switch (which) {
            case 0:  B = Wq;  Out = qlin;  break;
            case 1:  B = Wk;  Out = klin;  break;
            case 2:  B = Wv;  Out = vlin;  break;
            case 3:  B = Wgv; Out = gvlin; break;
            default: B = Wgo; Out = golin; break;
        }
    } else if (cb == 40) { B = WIq; Out = qI; N = HIN * DI; n0 = 0; }
    else                 { B = WIk; Out = kI; N = HIN * DI; n0 = 0; }
    gemm_tile_body(x, B, Out, blockIdx.y * 128, n0, N);
}

__global__ __launch_bounds__(256) void gemm_single_kernel(
    const float* __restrict__ A, const float* __restrict__ B, float* __restrict__ Cm, int N)
{
    gemm_tile_body(A, B, Cm, blockIdx.y * 128, blockIdx.x * 128, N);
}

__global__ void proj_w_kernel(const float* __restrict__ x, const float* __restrict__ WIw,
                              float* __restrict__ wsig)
{
    const int idx = blockIdx.x * 256 + threadIdx.x;   // t*4 + hi
    const int t = idx >> 2, hi = idx & 3;
    const float4* xr = (const float4*)(x + (size_t)t * C_DIM);
    const float4* wr = (const float4*)(WIw + (size_t)hi * C_DIM);
    float s = 0.f;
    for (int i = 0; i < C_DIM / 4; ++i) {
        float4 a = xr[i], b = wr[i];
        s += a.x * b.x + a.y * b.y + a.z * b.z + a.w * b.w;
    }
    wsig[idx] = sigf(s);
}

__global__ void transpose_kI_kernel(const float* __restrict__ kI, float* __restrict__ kIt)
{
    const int idx = blockIdx.x * 256 + threadIdx.x;  // (hi*32+d)*2048 + k
    const int k = idx & (T_SEQ - 1);
    const int d = (idx >> 11) & 31;
    const int hi = idx >> 16;
    kIt[idx] = kI[(size_t)k * (HIN * DI) + hi * DI + d];
}

__global__ void rope_table_kernel(float* __restrict__ cost, float* __restrict__ sint)
{
    const int idx = blockIdx.x * 256 + threadIdx.x;   // t*32 + i
    const int t = idx >> 5, i = idx & 31;
    const int j = (2 * i) & 31;
    const double invd = pow(10000.0, -(double)j / 32.0);
    const float invf = (float)invd;
    const float f = (float)t * invf;
    cost[idx] = (float)cos((double)f);
    sint[idx] = (float)sin((double)f);
}

__global__ void rope_v_kernel(
    const float* __restrict__ qlin, const float* __restrict__ klin,
    const float* __restrict__ vlin, const float* __restrict__ gvlin,
    const float* __restrict__ cost, const float* __restrict__ sint,
    float* __restrict__ Q, float* __restrict__ K, float* __restrict__ V)
{
    const int idx = blockIdx.x * 256 + threadIdx.x;   // (t*16+h)*32 + i
    const int i = idx & 31;
    const int h = (idx >> 5) & 15;
    const int t = idx >> 9;
    const float cv = cost[t * 32 + i], sv = sint[t * 32 + i];
    const size_t src = (size_t)t * C_DIM + h * HD + 2 * i;
    const float2 q2 = *(const float2*)(qlin + src);
    const float2 k2 = *(const float2*)(klin + src);
    const float2 v2 = *(const float2*)(vlin + src);
    const float2 g2 = *(const float2*)(gvlin + src);
    const size_t dst = ((size_t)h * T_SEQ + t) * HD;
    Q[dst + i]      = q2.x * cv - q2.y * sv;
    Q[dst + 32 + i] = q2.x * sv + q2.y * cv;
    K[dst + i]      = k2.x * cv - k2.y * sv;
    K[dst + 32 + i] = k2.x * sv + k2.y * cv;
    float2 vo;
    vo.x = v2.x * sigf(g2.x);
    vo.y = v2.y * sigf(g2.y);
    *(float2*)(V + dst + 2 * i) = vo;
}

// ---------------- wave-per-row indexer: dots + var -> k_t + radix-select ----------------
// One wave handles one (q, hi) row. 2048 keys live in registers (32/lane).
// Key ordering: (value_bits desc, index asc) == jax.lax.top_k stable order.
// Emits compacted u16 list: idx(11b) | head_mask(4b)<<11, ascending idx, + count.
__global__ __launch_bounds__(256) void indexer_kernel(
    const float* __restrict__ qI, const float* __restrict__ kIt,
    const float* __restrict__ wsig,
    const float* __restrict__ gate_bias, const float* __restrict__ head_bias,
    unsigned short* __restrict__ sidxg, unsigned* __restrict__ cnts)
{
    const int wv = threadIdx.x >> 6;
    const int lane = threadIdx.x & 63;
    const int q = blockIdx.x * 4 + wv;
    const int hi = blockIdx.y;
    const unsigned long long lmask_lt = (lane == 0) ? 0ull : ((~0ull) >> (64 - lane));

    // load q_I row (wave-uniform) into registers
    float qv[DI];
    {
        const float4* qp = (const float4*)(qI + (size_t)q * (HIN * DI) + hi * DI);
#pragma unroll
        for (int i = 0; i < DI / 4; ++i) {
            float4 t = qp[i];
            qv[4*i+0] = t.x; qv[4*i+1] = t.y; qv[4*i+2] = t.z; qv[4*i+3] = t.w;
        }
    }
    const float wr = wsig[q * HIN + hi];
    const float gb = gate_bias[hi];
    const float* kbase = kIt + (size_t)hi * DI * T_SEQ;

    unsigned ordv[32];
    double dsum = 0.0, dsq = 0.0;
#pragma unroll
    for (int i = 0; i < 32; ++i) {
        const int k = i * 64 + lane;
        float dot = 0.f;
#pragma unroll
        for (int d = 0; d < DI; ++d)
            dot = fmaf(qv[d], kbase[(size_t)d * T_SEQ + k], dot);
        unsigned vb;
        if (k <= q) {
            const float g = sigf(dot + gb);
            const float imp = wr * g;
            dsum += (double)imp;
            dsq  += (double)imp * (double)imp;
            vb = (k < SINKN) ? 0x7F800000u : __float_as_uint(imp);
        } else {
            vb = (k < SINKN) ? 0x7F800000u : 0u;
        }
        ordv[i] = vb;
    }

    // wave all-reduce (every lane ends with the full sums)
#pragma unroll
    for (int off = 1; off < 64; off <<= 1) {
        dsum += __shfl_xor(dsum, off);
        dsq  += __shfl_xor(dsq, off);
    }

    int kts[4];
#pragma unroll
    for (int j = 0; j < 4; ++j) {
        const float sh = sigf(head_bias[hi * 4 + j]);
        const double mean = dsum / (double)T_SEQ;
        double var = dsq / (double)T_SEQ - mean * mean;
        if (var < 0.0) var = 0.0;
        const double vh = var * (double)sh * (double)sh;
        int kt = (int)floor(512.0 * vh);
        kt = kt < KMINV ? KMINV : (kt > KMAXV ? KMAXV : kt);
        kts[j] = kt;
    }

    // per-head threshold (v*, tie_take) via MSB bitwise radix descent; dedupe equal k_t.
    unsigned vs[4]; int tt[4];
#pragma unroll
    for (int j = 0; j < 4; ++j) {
        bool dup = false;
#pragma unroll
        for (int p = 0; p < 4; ++p) {
            if (p < j && !dup && kts[p] == kts[j]) { vs[j] = vs[p]; tt[j] = tt[p]; dup = true; }
        }
        if (!dup) {
            unsigned P = 0; int Kp = kts[j];
#pragma unroll 1
            for (int b = 30; b >= 0; --b) {
                const unsigned cand = (P >> b) | 1u;
                int c = 0;
#pragma unroll
                for (int i = 0; i < 32; ++i) c += ((ordv[i] >> b) == cand) ? 1 : 0;
#pragma unroll
                for (int off = 1; off < 64; off <<= 1) c += __shfl_xor(c, off);
                if (c >= Kp) P |= (1u << b);
                else Kp -= c;
            }
            vs[j] = P; tt[j] = Kp;
        }
    }

    // emission: ascending k, ballot-compacted; ties at v* taken in index order.
    unsigned cnt = 0;
    int eqr0 = 0, eqr1 = 0, eqr2 = 0, eqr3 = 0;
    unsigned short* sp = sidxg + ((size_t)hi * T_SEQ + q) * KMAXV;
#pragma unroll
    for (int i = 0; i < 32; ++i) {
        const int k = i * 64 + lane;
        const unsigned x = ordv[i];
        unsigned mask = 0;
        {
            const bool eq = (x == vs[0]);
            const unsigned long long beq = __ballot(eq);
            const bool sel = (x > vs[0]) || (eq && (eqr0 + (int)__popcll(beq & lmask_lt) < tt[0]));
            eqr0 += (int)__popcll(beq);
            if (sel) mask |= 1u;
        }
        {
            const bool eq = (x == vs[1]);
            const unsigned long long beq = __ballot(eq);
            const bool sel = (x > vs[1]) || (eq && (eqr1 + (int)__popcll(beq & lmask_lt) < tt[1]));
            eqr1 += (int)__popcll(beq);
            if (sel) mask |= 2u;
        }
        {
            const bool eq = (x == vs[2]);
            const unsigned long long beq = __ballot(eq);
            const bool sel = (x > vs[2]) || (eq && (eqr2 + (int)__popcll(beq & lmask_lt) < tt[2]));
            eqr2 += (int)__popcll(beq);
            if (sel) mask |= 4u;
        }
        {
            const bool eq = (x == vs[3]);
            const unsigned long long beq = __ballot(eq);
            const bool sel = (x > vs[3]) || (eq && (eqr3 + (int)__popcll(beq & lmask_lt) < tt[3]));
            eqr3 += (int)__popcll(beq);
            if (sel) mask |= 8u;
        }
        const bool valid = (k <= q) && (mask != 0u);
        const unsigned long long bv = __ballot(valid);
        if (valid) {
            const unsigned pos = cnt + (unsigned)__popcll(bv & lmask_lt);
            sp[pos] = (unsigned short)((unsigned)k | (mask << 11));
        }
        cnt += (unsigned)__popcll(bv);
    }
    if (lane == 0) cnts[(size_t)hi * T_SEQ + q] = cnt;
}

// sparse gather attention: one wave per (head, query), list-driven with head-mask bits
__global__ __launch_bounds__(256) void attn_sparse_kernel(
    const float* __restrict__ Q, const float* __restrict__ K, const float* __restrict__ V,
    const unsigned short* __restrict__ sidx, const unsigned* __restrict__ cnts,
    float* __restrict__ o_flat)
{
    const int h  = blockIdx.y;
    const int hi = h >> 2, hj = h & 3;
    const int wv = threadIdx.x >> 6;
    const int lane = threadIdx.x & 63;
    const int q = blockIdx.x * 4 + wv;

    const size_t hq = (size_t)hi * T_SEQ + q;
    const int nv = (int)cnts[hq];

    const float qd = Q[((size_t)h * T_SEQ + q) * HD + lane];  // lane = dim
    const unsigned short* sp = sidx + hq * KMAXV;
    const float* Kh = K + (size_t)h * T_SEQ * HD;
    const float* Vh = V + (size_t)h * T_SEQ * HD;

    float m = -INFINITY, l = 0.f, o = 0.f;

    for (int base = 0; base < nv; base += 64) {
        const int nk = min(64, nv - base);
        const unsigned e = (lane < nk) ? (unsigned)sp[base + lane] : 0u;
        const int idxv = (int)(e & 0x7FFu);
        const bool ok = (lane < nk) && ((e >> (11 + hj)) & 1u);

        const float4* kr = (const float4*)(Kh + (size_t)idxv * HD);
        float acc = 0.f;
#pragma unroll
        for (int d4 = 0; d4 < 16; ++d4) {
            float4 kv = kr[d4];
            acc = fmaf(__shfl(qd, d4 * 4 + 0), kv.x, acc);
            acc = fmaf(__shfl(qd, d4 * 4 + 1), kv.y, acc);
            acc = fmaf(__shfl(qd, d4 * 4 + 2), kv.z, acc);
            acc = fmaf(__shfl(qd, d4 * 4 + 3), kv.w, acc);
        }
        float s = ok ? acc * 0.125f : -INFINITY;

        float cm = s;
#pragma unroll
        for (int off = 32; off > 0; off >>= 1) cm = fmaxf(cm, __shfl_xor(cm, off));
        const float mn = fmaxf(m, cm);
        if (mn > -INFINITY) {
            const float alpha = expf(m - mn);
            const float p = expf(s - mn);   // exp(-inf)=0 for masked lanes
            float ls = p;
#pragma unroll
            for (int off = 32; off > 0; off >>= 1) ls += __shfl_xor(ls, off);
            l = l * alpha + ls;
            o = o * alpha;
            for (int k = 0; k < nk; ++k) {
                const float pk = __shfl(p, k);
                const int iv = __shfl(idxv, k);
                o = fmaf(pk, Vh[(size_t)iv * HD + lane], o);
            }
            m = mn;
        }
    }
    const float invl = 1.f / l;
    o_flat[(size_t)q * C_DIM + h * HD + lane] = o * invl;
}

__global__ void gate_o_kernel(const float* __restrict__ o_flat, const float* __restrict__ golin,
                              float* __restrict__ og)
{
    const int idx = blockIdx.x * 256 + threadIdx.x;
    og[idx] = o_flat[idx] * sigf(golin[idx]);
}

extern "C" void kernel_launch(void* const* d_in, const int* in_sizes, int n_in,
                              void* d_out, int out_size, void* d_ws, size_t ws_size,
                              hipStream_t stream)
{
    const float* x   = (const float*)d_in[0];
    const float* WIq = (const float*)d_in[1];
    const float* WIk = (const float*)d_in[2];
    const float* WIw = (const float*)d_in[3];
    const float* gb  = (const float*)d_in[4];
    const float* hib = (const float*)d_in[5];
    const float* Wq  = (const float*)d_in[6];
    const float* Wk  = (const float*)d_in[7];
    const float* Wv  = (const float*)d_in[8];
    const float* Wgv = (const float*)d_in[9];
    const float* Wgo = (const float*)d_in[10];
    const float* Wo  = (const float*)d_in[11];
    float* out = (float*)d_out;

    char* ws = (char*)d_ws;
    const size_t MB = 1024 * 1024;
    float*    qI    = (float*)(ws + 0 * MB);                 // 1 MB
    float*    kI    = (float*)(ws + 1 * MB);                 // 1 MB
    float*    kIt   = (float*)(ws + 2 * MB);                 // 1 MB
    float*    wsig  = (float*)(ws + 3 * MB);                 // 32 KB
    unsigned* cnts  = (unsigned*)(ws + 3 * MB + 64 * 1024);  // 32 KB
    float*    cost  = (float*)(ws + 3 * MB + 512 * 1024);    // 256 KB
    float*    sint  = (float*)(ws + 3 * MB + 768 * 1024);    // 256 KB
    float*    Q     = (float*)(ws + 4 * MB);                 // 8 MB
    float*    K     = (float*)(ws + 12 * MB);                // 8 MB
    float*    V     = (float*)(ws + 20 * MB);                // 8 MB
    float*    qlin  = (float*)(ws + 28 * MB);                // 8 MB
    float*    klin  = (float*)(ws + 36 * MB);                // 8 MB
    float*    vlin  = (float*)(ws + 44 * MB);                // 8 MB
    float*    gvlin = (float*)(ws + 52 * MB);                // 8 MB
    float*    golin = (float*)(ws + 60 * MB);                // 8 MB -> 68 MB total
    // overlays (dead-after-rope regions):
    unsigned short* sidx = (unsigned short*)(ws + 44 * MB);  // 16 MB over vlin+gvlin
    float*    o_flat = qlin;   // dead after rope_v
    float*    og     = klin;   // dead after rope_v

    gemm_proj_kernel<<<dim3(42, 16), 256, 0, stream>>>(
        x, Wq, Wk, Wv, Wgv, Wgo, WIq, WIk,
        qlin, klin, vlin, gvlin, golin, qI, kI);
    proj_w_kernel<<<dim3(32), 256, 0, stream>>>(x, WIw, wsig);
    transpose_kI_kernel<<<dim3(1024), 256, 0, stream>>>(kI, kIt);
    rope_table_kernel<<<dim3(256), 256, 0, stream>>>(cost, sint);
    rope_v_kernel<<<dim3(4096), 256, 0, stream>>>(qlin, klin, vlin, gvlin, cost, sint, Q, K, V);
    indexer_kernel<<<dim3(512, 4), 256, 0, stream>>>(qI, kIt, wsig, gb, hib, sidx, cnts);
    attn_sparse_kernel<<<dim3(512, 16), 256, 0, stream>>>(Q, K, V, sidx, cnts, o_flat);
    gate_o_kernel<<<dim3(8192), 256, 0, stream>>>(o_flat, golin, og);
    gemm_single_kernel<<<dim3(8, 16), 256, 0, stream>>>(og, Wo, out, C_DIM);
}

// Round 4
// 503.882 us; speedup vs baseline: 3.1362x; 1.4315x over previous
//
#include <hip/hip_runtime.h>
#include <math.h>

#define T_SEQ 2048
#define C_DIM 1024
#define NH    16
#define HD    64
#define HIN   4
#define DI    32
#define SINKN 4
#define KMINV 32
#define KMAXV 1024
#define NCAT  5120   // q|k|v|gv|go concatenated columns

typedef __bf16 bf16x8 __attribute__((ext_vector_type(8)));
typedef float  f32x4  __attribute__((ext_vector_type(4)));

__device__ __forceinline__ float sigf(float x) { return 1.f / (1.f + expf(-x)); }

__device__ __forceinline__ unsigned short f2bf(float f) {
    unsigned u = __float_as_uint(f);
    unsigned r = (u + 0x7FFFu + ((u >> 16) & 1u)) >> 16;   // RNE
    return (unsigned short)r;
}

__device__ __forceinline__ void gload16(const unsigned short* g, unsigned short* l) {
    __builtin_amdgcn_global_load_lds(
        (const __attribute__((address_space(1))) unsigned int*)(const unsigned int*)g,
        (__attribute__((address_space(3))) unsigned int*)(unsigned int*)l,
        16, 0, 0);
}

// ---------------- bf16 MFMA GEMM: C(f32) = A_bf16 @ B_bf16^T ----------------
// A: M x 1024, B: N x 1024 (row-major bf16), tile 128x128, BK=64,
// 4 waves (2x2), each wave 64x64 via 4x4 frags of mfma_f32_16x16x32_bf16.
// LDS linear-write via global_load_lds; XOR swizzle (slot ^= row&7) applied on
// the global source (store side) and on ds_read addresses (read side).
__global__ __launch_bounds__(256) void gemm_bf16_kernel(
    const unsigned short* __restrict__ A, const unsigned short* __restrict__ B,
    float* __restrict__ C, int ldc)
{
    __shared__ unsigned short Asl[128 * 64];
    __shared__ unsigned short Bsl[128 * 64];
    const int K = C_DIM;
    const int tid = threadIdx.x;
    const int w = tid >> 6, lane = tid & 63;
    const int wm = w >> 1, wn = w & 1;
    const int m0 = blockIdx.y * 128, n0 = blockIdx.x * 128;

    const f32x4 z4 = {0.f, 0.f, 0.f, 0.f};
    f32x4 acc[4][4];
#pragma unroll
    for (int i = 0; i < 4; ++i)
#pragma unroll
        for (int j = 0; j < 4; ++j) acc[i][j] = z4;

    // staging: per instruction i (0..3), wave w covers rows i*32 + w*8 + (lane>>3)
    const int lrow  = w * 8 + (lane >> 3);             // + i*32
    const int lslot = (lane & 7) ^ (lane >> 3);        // pre-swizzled source slot
    const unsigned short* Ag = A + (size_t)(m0 + lrow) * K + lslot * 8;
    const unsigned short* Bg = B + (size_t)(n0 + lrow) * K + lslot * 8;

    // read-side fragment addressing (row, k-slot) with same swizzle
    const int fr = lane & 15;          // frag row (A) / col (B)
    const int kg = lane >> 4;          // k-group

    for (int kt = 0; kt < K; kt += 64) {
        __syncthreads();
#pragma unroll
        for (int i = 0; i < 4; ++i) {
            gload16(Ag + (size_t)(i * 32) * K + kt, &Asl[(i * 32 + w * 8) * 64]);
            gload16(Bg + (size_t)(i * 32) * K + kt, &Bsl[(i * 32 + w * 8) * 64]);
        }
        __syncthreads();   // drains vmcnt(0) then barrier -> LDS tile ready
#pragma unroll
        for (int ks = 0; ks < 2; ++ks) {
            bf16x8 af[4], bfr[4];
            const int aslot = ks * 4 + kg;
#pragma unroll
            for (int f = 0; f < 4; ++f) {
                const int arow = wm * 64 + f * 16 + fr;
                af[f] = *(const bf16x8*)&Asl[arow * 64 + ((aslot ^ (arow & 7)) * 8)];
                const int brow = wn * 64 + f * 16 + fr;
                bfr[f] = *(const bf16x8*)&Bsl[brow * 64 + ((aslot ^ (brow & 7)) * 8)];
            }
#pragma unroll
            for (int mi = 0; mi < 4; ++mi)
#pragma unroll
                for (int ni = 0; ni < 4; ++ni)
                    acc[mi][ni] = __builtin_amdgcn_mfma_f32_16x16x32_bf16(
                        af[mi], bfr[ni], acc[mi][ni], 0, 0, 0);
        }
    }

    // epilogue: C/D layout col=lane&15, row=(lane>>4)*4+reg
#pragma unroll
    for (int mi = 0; mi < 4; ++mi) {
        const int row = m0 + wm * 64 + mi * 16 + (lane >> 4) * 4;
#pragma unroll
        for (int ni = 0; ni < 4; ++ni) {
            const int col = n0 + wn * 64 + ni * 16 + (lane & 15);
            float* cp = C + (size_t)row * ldc + col;
#pragma unroll
            for (int r = 0; r < 4; ++r) cp[(size_t)r * ldc] = acc[mi][ni][r];
        }
    }
}

// one-shot f32 -> bf16 conversion of x and all big weights
__global__ __launch_bounds__(256) void convert_all_kernel(
    const float* __restrict__ x,
    const float* __restrict__ Wq, const float* __restrict__ Wk, const float* __restrict__ Wv,
    const float* __restrict__ Wgv, const float* __restrict__ Wgo, const float* __restrict__ Wo,
    unsigned short* __restrict__ xb, unsigned short* __restrict__ Wcatb,
    unsigned short* __restrict__ Wob)
{
    const int b = blockIdx.x;
    const float* s; unsigned short* d; size_t off;
    if (b < 2048)      { s = x;  d = xb;  off = (size_t)b * 1024; }
    else if (b < 7168) {
        const int wsel = (b - 2048) >> 10;
        switch (wsel) {
            case 0: s = Wq;  break;
            case 1: s = Wk;  break;
            case 2: s = Wv;  break;
            case 3: s = Wgv; break;
            default: s = Wgo; break;
        }
        d = Wcatb + ((size_t)wsel << 20);
        off = (size_t)((b - 2048) & 1023) * 1024;
    } else             { s = Wo; d = Wob; off = (size_t)(b - 7168) * 1024; }

    const size_t i = off + threadIdx.x * 4;
    const float4 v = *(const float4*)(s + i);
    ushort4 o;
    o.x = f2bf(v.x); o.y = f2bf(v.y); o.z = f2bf(v.z); o.w = f2bf(v.w);
    *(ushort4*)(d + i) = o;
}

// ---------------- f32 GEMM tile (indexer path only, exact) ----------------
__device__ __forceinline__ void gemm_tile_body(
    const float* __restrict__ A, const float* __restrict__ B, float* __restrict__ Cm,
    int m0, int n0, int N)
{
    __shared__ float As[16][132];
    __shared__ float Bs[16][132];
    const int K = C_DIM;
    const int tid = threadIdx.x;
    const int tx = tid & 15, ty = tid >> 4;

    float acc[8][8];
#pragma unroll
    for (int i = 0; i < 8; ++i)
#pragma unroll
        for (int j = 0; j < 8; ++j) acc[i][j] = 0.f;

    const int sr = tid >> 1;
    const int sk = (tid & 1) * 8;
    const float* Ap = A + (size_t)(m0 + sr) * K + sk;
    const float* Bp = B + (size_t)(n0 + sr) * K + sk;

    for (int k0 = 0; k0 < K; k0 += 16) {
        float4 a0 = *(const float4*)(Ap + k0);
        float4 a1 = *(const float4*)(Ap + k0 + 4);
        float4 b0 = *(const float4*)(Bp + k0);
        float4 b1 = *(const float4*)(Bp + k0 + 4);
        __syncthreads();
        As[sk + 0][sr] = a0.x; As[sk + 1][sr] = a0.y; As[sk + 2][sr] = a0.z; As[sk + 3][sr] = a0.w;
        As[sk + 4][sr] = a1.x; As[sk + 5][sr] = a1.y; As[sk + 6][sr] = a1.z; As[sk + 7][sr] = a1.w;
        Bs[sk + 0][sr] = b0.x; Bs[sk + 1][sr] = b0.y; Bs[sk + 2][sr] = b0.z; Bs[sk + 3][sr] = b0.w;
        Bs[sk + 4][sr] = b1.x; Bs[sk + 5][sr] = b1.y; Bs[sk + 6][sr] = b1.z; Bs[sk + 7][sr] = b1.w;
        __syncthreads();
#pragma unroll
        for (int kk = 0; kk < 16; ++kk) {
            float4 aA = *(const float4*)&As[kk][ty * 4];
            float4 aB = *(const float4*)&As[kk][64 + ty * 4];
            float4 bA = *(const float4*)&Bs[kk][tx * 4];
            float4 bB = *(const float4*)&Bs[kk][64 + tx * 4];
            float am[8] = {aA.x, aA.y, aA.z, aA.w, aB.x, aB.y, aB.z, aB.w};
            float bn[8] = {bA.x, bA.y, bA.z, bA.w, bB.x, bB.y, bB.z, bB.w};
#pragma unroll
            for (int i = 0; i < 8; ++i)
#pragma unroll
                for (int j = 0; j < 8; ++j) acc[i][j] = fmaf(am[i], bn[j], acc[i][j]);
        }
    }

#pragma unroll
    for (int ih = 0; ih < 2; ++ih)
#pragma unroll
        for (int i = 0; i < 4; ++i) {
            const int row = m0 + ih * 64 + ty * 4 + i;
            float* cp = Cm + (size_t)row * N + n0;
            float4 v0 = make_float4(acc[ih*4+i][0], acc[ih*4+i][1], acc[ih*4+i][2], acc[ih*4+i][3]);
            float4 v1 = make_float4(acc[ih*4+i][4], acc[ih*4+i][5], acc[ih*4+i][6], acc[ih*4+i][7]);
            *(float4*)(cp + tx * 4) = v0;
            *(float4*)(cp + 64 + tx * 4) = v1;
        }
}

__global__ __launch_bounds__(256) void gemm_qik_kernel(
    const float* __restrict__ x, const float* __restrict__ WIq, const float* __restrict__ WIk,
    float* __restrict__ qI, float* __restrict__ kI)
{
    if (blockIdx.x == 0) gemm_tile_body(x, WIq, qI, blockIdx.y * 128, 0, HIN * DI);
    else                 gemm_tile_body(x, WIk, kI, blockIdx.y * 128, 0, HIN * DI);
}

__global__ void proj_w_kernel(const float* __restrict__ x, const float* __restrict__ WIw,
                              float* __restrict__ wsig)
{
    const int idx = blockIdx.x * 256 + threadIdx.x;   // t*4 + hi
    const int t = idx >> 2, hi = idx & 3;
    const float4* xr = (const float4*)(x + (size_t)t * C_DIM);
    const float4* wr = (const float4*)(WIw + (size_t)hi * C_DIM);
    float s = 0.f;
    for (int i = 0; i < C_DIM / 4; ++i) {
        float4 a = xr[i], b = wr[i];
        s += a.x * b.x + a.y * b.y + a.z * b.z + a.w * b.w;
    }
    wsig[idx] = sigf(s);
}

__global__ void transpose_kI_kernel(const float* __restrict__ kI, float* __restrict__ kIt)
{
    const int idx = blockIdx.x * 256 + threadIdx.x;  // (hi*32+d)*2048 + k
    const int k = idx & (T_SEQ - 1);
    const int d = (idx >> 11) & 31;
    const int hi = idx >> 16;
    kIt[idx] = kI[(size_t)k * (HIN * DI) + hi * DI + d];
}

__global__ void rope_table_kernel(float* __restrict__ cost, float* __restrict__ sint)
{
    const int idx = blockIdx.x * 256 + threadIdx.x;   // t*32 + i
    const int t = idx >> 5, i = idx & 31;
    const int j = (2 * i) & 31;
    const double invd = pow(10000.0, -(double)j / 32.0);
    const float invf = (float)invd;
    const float f = (float)t * invf;
    cost[idx] = (float)cos((double)f);
    sint[idx] = (float)sin((double)f);
}

// RoPE + v*sig(gv); reads the concatenated projection buffer (row stride 5120)
__global__ void rope_v_kernel(
    const float* __restrict__ lincat,
    const float* __restrict__ cost, const float* __restrict__ sint,
    float* __restrict__ Q, float* __restrict__ K, float* __restrict__ V)
{
    const int idx = blockIdx.x * 256 + threadIdx.x;   // (t*16+h)*32 + i
    const int i = idx & 31;
    const int h = (idx >> 5) & 15;
    const int t = idx >> 9;
    const float cv = cost[t * 32 + i], sv = sint[t * 32 + i];
    const size_t src = (size_t)t * NCAT + h * HD + 2 * i;
    const float2 q2 = *(const float2*)(lincat + src);
    const float2 k2 = *(const float2*)(lincat + src + 1024);
    const float2 v2 = *(const float2*)(lincat + src + 2048);
    const float2 g2 = *(const float2*)(lincat + src + 3072);
    const size_t dst = ((size_t)h * T_SEQ + t) * HD;
    Q[dst + i]      = q2.x * cv - q2.y * sv;
    Q[dst + 32 + i] = q2.x * sv + q2.y * cv;
    K[dst + i]      = k2.x * cv - k2.y * sv;
    K[dst + 32 + i] = k2.x * sv + k2.y * cv;
    float2 vo;
    vo.x = v2.x * sigf(g2.x);
    vo.y = v2.y * sigf(g2.y);
    *(float2*)(V + dst + 2 * i) = vo;
}

// ---------------- wave-per-row indexer: dots + var -> k_t + radix-select ----------------
__global__ __launch_bounds__(256) void indexer_kernel(
    const float* __restrict__ qI, const float* __restrict__ kIt,
    const float* __restrict__ wsig,
    const float* __restrict__ gate_bias, const float* __restrict__ head_bias,
    unsigned short* __restrict__ sidxg, unsigned* __restrict__ cnts)
{
    const int wv = threadIdx.x >> 6;
    const int lane = threadIdx.x & 63;
    const int q = blockIdx.x * 4 + wv;
    const int hi = blockIdx.y;
    const unsigned long long lmask_lt = (lane == 0) ? 0ull : ((~0ull) >> (64 - lane));

    float qv[DI];
    {
        const float4* qp = (const float4*)(qI + (size_t)q * (HIN * DI) + hi * DI);
#pragma unroll
        for (int i = 0; i < DI / 4; ++i) {
            float4 t = qp[i];
            qv[4*i+0] = t.x; qv[4*i+1] = t.y; qv[4*i+2] = t.z; qv[4*i+3] = t.w;
        }
    }
    const float wr = wsig[q * HIN + hi];
    const float gb = gate_bias[hi];
    const float* kbase = kIt + (size_t)hi * DI * T_SEQ;

    unsigned ordv[32];
    double dsum = 0.0, dsq = 0.0;
#pragma unroll
    for (int i = 0; i < 32; ++i) {
        const int k = i * 64 + lane;
        float dot = 0.f;
#pragma unroll
        for (int d = 0; d < DI; ++d)
            dot = fmaf(qv[d], kbase[(size_t)d * T_SEQ + k], dot);
        unsigned vb;
        if (k <= q) {
            const float g = sigf(dot + gb);
            const float imp = wr * g;
            dsum += (double)imp;
            dsq  += (double)imp * (double)imp;
            vb = (k < SINKN) ? 0x7F800000u : __float_as_uint(imp);
        } else {
            vb = (k < SINKN) ? 0x7F800000u : 0u;
        }
        ordv[i] = vb;
    }

#pragma unroll
    for (int off = 1; off < 64; off <<= 1) {
        dsum += __shfl_xor(dsum, off);
        dsq  += __shfl_xor(dsq, off);
    }

    int kts[4];
#pragma unroll
    for (int j = 0; j < 4; ++j) {
        const float sh = sigf(head_bias[hi * 4 + j]);
        const double mean = dsum / (double)T_SEQ;
        double var = dsq / (double)T_SEQ - mean * mean;
        if (var < 0.0) var = 0.0;
        const double vh = var * (double)sh * (double)sh;
        int kt = (int)floor(512.0 * vh);
        kt = kt < KMINV ? KMINV : (kt > KMAXV ? KMAXV : kt);
        kts[j] = kt;
    }

    unsigned vs[4]; int tt[4];
#pragma unroll
    for (int j = 0; j < 4; ++j) {
        bool dup = false;
#pragma unroll
        for (int p = 0; p < 4; ++p) {
            if (p < j && !dup && kts[p] == kts[j]) { vs[j] = vs[p]; tt[j] = tt[p]; dup = true; }
        }
        if (!dup) {
            unsigned P = 0; int Kp = kts[j];
#pragma unroll 1
            for (int b = 30; b >= 0; --b) {
                const unsigned cand = (P >> b) | 1u;
                int c = 0;
#pragma unroll
                for (int i = 0; i < 32; ++i) c += ((ordv[i] >> b) == cand) ? 1 : 0;
#pragma unroll
                for (int off = 1; off < 64; off <<= 1) c += __shfl_xor(c, off);
                if (c >= Kp) P |= (1u << b);
                else Kp -= c;
            }
            vs[j] = P; tt[j] = Kp;
        }
    }

    unsigned cnt = 0;
    int eqr0 = 0, eqr1 = 0, eqr2 = 0, eqr3 = 0;
    unsigned short* sp = sidxg + ((size_t)hi * T_SEQ + q) * KMAXV;
#pragma unroll
    for (int i = 0; i < 32; ++i) {
        const int k = i * 64 + lane;
        const unsigned x = ordv[i];
        unsigned mask = 0;
        {
            const bool eq = (x == vs[0]);
            const unsigned long long beq = __ballot(eq);
            const bool sel = (x > vs[0]) || (eq && (eqr0 + (int)__popcll(beq & lmask_lt) < tt[0]));
            eqr0 += (int)__popcll(beq);
            if (sel) mask |= 1u;
        }
        {
            const bool eq = (x == vs[1]);
            const unsigned long long beq = __ballot(eq);
            const bool sel = (x > vs[1]) || (eq && (eqr1 + (int)__popcll(beq & lmask_lt) < tt[1]));
            eqr1 += (int)__popcll(beq);
            if (sel) mask |= 2u;
        }
        {
            const bool eq = (x == vs[2]);
            const unsigned long long beq = __ballot(eq);
            const bool sel = (x > vs[2]) || (eq && (eqr2 + (int)__popcll(beq & lmask_lt) < tt[2]));
            eqr2 += (int)__popcll(beq);
            if (sel) mask |= 4u;
        }
        {
            const bool eq = (x == vs[3]);
            const unsigned long long beq = __ballot(eq);
            const bool sel = (x > vs[3]) || (eq && (eqr3 + (int)__popcll(beq & lmask_lt) < tt[3]));
            eqr3 += (int)__popcll(beq);
            if (sel) mask |= 8u;
        }
        const bool valid = (k <= q) && (mask != 0u);
        const unsigned long long bv = __ballot(valid);
        if (valid) {
            const unsigned pos = cnt + (unsigned)__popcll(bv & lmask_lt);
            sp[pos] = (unsigned short)((unsigned)k | (mask << 11));
        }
        cnt += (unsigned)__popcll(bv);
    }
    if (lane == 0) cnts[(size_t)hi * T_SEQ + q] = cnt;
}

// sparse gather attention + fused output gate; writes bf16 og directly
__global__ __launch_bounds__(256) void attn_sparse_kernel(
    const float* __restrict__ Q, const float* __restrict__ K, const float* __restrict__ V,
    const unsigned short* __restrict__ sidx, const unsigned* __restrict__ cnts,
    const float* __restrict__ lincat, unsigned short* __restrict__ ogb)
{
    const int h  = blockIdx.y;
    const int hi = h >> 2, hj = h & 3;
    const int wv = threadIdx.x >> 6;
    const int lane = threadIdx.x & 63;
    const int q = blockIdx.x * 4 + wv;

    const size_t hq = (size_t)hi * T_SEQ + q;
    const int nv = (int)cnts[hq];

    const float qd = Q[((size_t)h * T_SEQ + q) * HD + lane];  // lane = dim
    const unsigned short* sp = sidx + hq * KMAXV;
    const float* Kh = K + (size_t)h * T_SEQ * HD;
    const float* Vh = V + (size_t)h * T_SEQ * HD;

    float m = -INFINITY, l = 0.f, o = 0.f;

    for (int base = 0; base < nv; base += 64) {
        const int nk = min(64, nv - base);
        const unsigned e = (lane < nk) ? (unsigned)sp[base + lane] : 0u;
        const int idxv = (int)(e & 0x7FFu);
        const bool ok = (lane < nk) && ((e >> (11 + hj)) & 1u);

        const float4* kr = (const float4*)(Kh + (size_t)idxv * HD);
        float acc = 0.f;
#pragma unroll
        for (int d4 = 0; d4 < 16; ++d4) {
            float4 kv = kr[d4];
            acc = fmaf(__shfl(qd, d4 * 4 + 0), kv.x, acc);
            acc = fmaf(__shfl(qd, d4 * 4 + 1), kv.y, acc);
            acc = fmaf(__shfl(qd, d4 * 4 + 2), kv.z, acc);
            acc = fmaf(__shfl(qd, d4 * 4 + 3), kv.w, acc);
        }
        float s = ok ? acc * 0.125f : -INFINITY;

        float cm = s;
#pragma unroll
        for (int off = 32; off > 0; off >>= 1) cm = fmaxf(cm, __shfl_xor(cm, off));
        const float mn = fmaxf(m, cm);
        if (mn > -INFINITY) {
            const float alpha = expf(m - mn);
            const float p = expf(s - mn);
            float ls = p;
#pragma unroll
            for (int off = 32; off > 0; off >>= 1) ls += __shfl_xor(ls, off);
            l = l * alpha + ls;
            o = o * alpha;
            for (int k = 0; k < nk; ++k) {
                const float pk = __shfl(p, k);
                const int iv = __shfl(idxv, k);
                o = fmaf(pk, Vh[(size_t)iv * HD + lane], o);
            }
            m = mn;
        }
    }
    const float invl = 1.f / l;
    const float gg = lincat[(size_t)q * NCAT + 4096 + h * HD + lane];
    ogb[(size_t)q * C_DIM + h * HD + lane] = f2bf(o * invl * sigf(gg));
}

extern "C" void kernel_launch(void* const* d_in, const int* in_sizes, int n_in,
                              void* d_out, int out_size, void* d_ws, size_t ws_size,
                              hipStream_t stream)
{
    const float* x   = (const float*)d_in[0];
    const float* WIq = (const float*)d_in[1];
    const float* WIk = (const float*)d_in[2];
    const float* WIw = (const float*)d_in[3];
    const float* gb  = (const float*)d_in[4];
    const float* hib = (const float*)d_in[5];
    const float* Wq  = (const float*)d_in[6];
    const float* Wk  = (const float*)d_in[7];
    const float* Wv  = (const float*)d_in[8];
    const float* Wgv = (const float*)d_in[9];
    const float* Wgo = (const float*)d_in[10];
    const float* Wo  = (const float*)d_in[11];
    float* out = (float*)d_out;

    char* ws = (char*)d_ws;
    const size_t MB = 1024 * 1024;
    float*    qI     = (float*)(ws + 0 * MB);                 // 1 MB
    float*    kI     = (float*)(ws + 1 * MB);                 // 1 MB
    float*    kIt    = (float*)(ws + 2 * MB);                 // 1 MB
    float*    wsig   = (float*)(ws + 3 * MB);                 // 32 KB
    unsigned* cnts   = (unsigned*)(ws + 3 * MB + 64 * 1024);  // 32 KB
    float*    cost   = (float*)(ws + 3 * MB + 512 * 1024);    // 256 KB
    float*    sint   = (float*)(ws + 3 * MB + 768 * 1024);    // 256 KB
    float*    Q      = (float*)(ws + 4 * MB);                 // 8 MB
    float*    K      = (float*)(ws + 12 * MB);                // 8 MB
    float*    V      = (float*)(ws + 20 * MB);                // 8 MB
    float*    lincat = (float*)(ws + 28 * MB);                // 40 MB -> 68
    unsigned short* sidx  = (unsigned short*)(ws + 68 * MB);  // 16 MB -> 84
    unsigned short* xb    = (unsigned short*)(ws + 84 * MB);  // 4 MB -> 88
    unsigned short* Wcatb = (unsigned short*)(ws + 88 * MB);  // 10 MB -> 98
    unsigned short* Wob   = (unsigned short*)(ws + 98 * MB);  // 2 MB -> 100
    unsigned short* ogb   = (unsigned short*)(ws + 100 * MB); // 4 MB -> 104

    convert_all_kernel<<<dim3(8192), 256, 0, stream>>>(
        x, Wq, Wk, Wv, Wgv, Wgo, Wo, xb, Wcatb, Wob);
    gemm_bf16_kernel<<<dim3(40, 16), 256, 0, stream>>>(xb, Wcatb, lincat, NCAT);
    gemm_qik_kernel<<<dim3(2, 16), 256, 0, stream>>>(x, WIq, WIk, qI, kI);
    proj_w_kernel<<<dim3(32), 256, 0, stream>>>(x, WIw, wsig);
    transpose_kI_kernel<<<dim3(1024), 256, 0, stream>>>(kI, kIt);
    rope_table_kernel<<<dim3(256), 256, 0, stream>>>(cost, sint);
    rope_v_kernel<<<dim3(4096), 256, 0, stream>>>(lincat, cost, sint, Q, K, V);
    indexer_kernel<<<dim3(512, 4), 256, 0, stream>>>(qI, kIt, wsig, gb, hib, sidx, cnts);
    attn_sparse_kernel<<<dim3(512, 16), 256, 0, stream>>>(Q, K, V, sidx, cnts, lincat, ogb);
    gemm_bf16_kernel<<<dim3(8, 16), 256, 0, stream>>>(ogb, Wob, out, C_DIM);
}

// Round 5
// 324.249 us; speedup vs baseline: 4.8737x; 1.5540x over previous
//
#include <hip/hip_runtime.h>
#include <math.h>

#define T_SEQ 2048
#define C_DIM 1024
#define NH    16
#define HD    64
#define HIN   4
#define DI    32
#define SINKN 4
#define KMINV 32
#define KMAXV 1024
#define NCAT  5120   // q|k|v|gv|go concatenated columns

typedef __bf16 bf16x8 __attribute__((ext_vector_type(8)));
typedef float  f32x4  __attribute__((ext_vector_type(4)));

__device__ __forceinline__ float sigf(float x) { return 1.f / (1.f + expf(-x)); }

__device__ __forceinline__ unsigned short f2bf(float f) {
    unsigned u = __float_as_uint(f);
    unsigned r = (u + 0x7FFFu + ((u >> 16) & 1u)) >> 16;   // RNE
    return (unsigned short)r;
}

__device__ __forceinline__ void gload16(const unsigned short* g, unsigned short* l) {
    __builtin_amdgcn_global_load_lds(
        (const __attribute__((address_space(1))) unsigned int*)(const unsigned int*)g,
        (__attribute__((address_space(3))) unsigned int*)(unsigned int*)l,
        16, 0, 0);
}

// ---------------- bf16 MFMA GEMM: C(f32) = A_bf16 @ B_bf16^T ----------------
__global__ __launch_bounds__(256) void gemm_bf16_kernel(
    const unsigned short* __restrict__ A, const unsigned short* __restrict__ B,
    float* __restrict__ C, int ldc)
{
    __shared__ unsigned short Asl[128 * 64];
    __shared__ unsigned short Bsl[128 * 64];
    const int K = C_DIM;
    const int tid = threadIdx.x;
    const int w = tid >> 6, lane = tid & 63;
    const int wm = w >> 1, wn = w & 1;
    const int m0 = blockIdx.y * 128, n0 = blockIdx.x * 128;

    const f32x4 z4 = {0.f, 0.f, 0.f, 0.f};
    f32x4 acc[4][4];
#pragma unroll
    for (int i = 0; i < 4; ++i)
#pragma unroll
        for (int j = 0; j < 4; ++j) acc[i][j] = z4;

    const int lrow  = w * 8 + (lane >> 3);
    const int lslot = (lane & 7) ^ (lane >> 3);
    const unsigned short* Ag = A + (size_t)(m0 + lrow) * K + lslot * 8;
    const unsigned short* Bg = B + (size_t)(n0 + lrow) * K + lslot * 8;

    const int fr = lane & 15;
    const int kg = lane >> 4;

    for (int kt = 0; kt < K; kt += 64) {
        __syncthreads();
#pragma unroll
        for (int i = 0; i < 4; ++i) {
            gload16(Ag + (size_t)(i * 32) * K + kt, &Asl[(i * 32 + w * 8) * 64]);
            gload16(Bg + (size_t)(i * 32) * K + kt, &Bsl[(i * 32 + w * 8) * 64]);
        }
        __syncthreads();
#pragma unroll
        for (int ks = 0; ks < 2; ++ks) {
            bf16x8 af[4], bfr[4];
            const int aslot = ks * 4 + kg;
#pragma unroll
            for (int f = 0; f < 4; ++f) {
                const int arow = wm * 64 + f * 16 + fr;
                af[f] = *(const bf16x8*)&Asl[arow * 64 + ((aslot ^ (arow & 7)) * 8)];
                const int brow = wn * 64 + f * 16 + fr;
                bfr[f] = *(const bf16x8*)&Bsl[brow * 64 + ((aslot ^ (brow & 7)) * 8)];
            }
#pragma unroll
            for (int mi = 0; mi < 4; ++mi)
#pragma unroll
                for (int ni = 0; ni < 4; ++ni)
                    acc[mi][ni] = __builtin_amdgcn_mfma_f32_16x16x32_bf16(
                        af[mi], bfr[ni], acc[mi][ni], 0, 0, 0);
        }
    }

#pragma unroll
    for (int mi = 0; mi < 4; ++mi) {
        const int row = m0 + wm * 64 + mi * 16 + (lane >> 4) * 4;
#pragma unroll
        for (int ni = 0; ni < 4; ++ni) {
            const int col = n0 + wn * 64 + ni * 16 + (lane & 15);
            float* cp = C + (size_t)row * ldc + col;
#pragma unroll
            for (int r = 0; r < 4; ++r) cp[(size_t)r * ldc] = acc[mi][ni][r];
        }
    }
}

// one-shot f32 -> bf16 conversion of x and all big weights
__global__ __launch_bounds__(256) void convert_all_kernel(
    const float* __restrict__ x,
    const float* __restrict__ Wq, const float* __restrict__ Wk, const float* __restrict__ Wv,
    const float* __restrict__ Wgv, const float* __restrict__ Wgo, const float* __restrict__ Wo,
    unsigned short* __restrict__ xb, unsigned short* __restrict__ Wcatb,
    unsigned short* __restrict__ Wob)
{
    const int b = blockIdx.x;
    const float* s; unsigned short* d; size_t off;
    if (b < 2048)      { s = x;  d = xb;  off = (size_t)b * 1024; }
    else if (b < 7168) {
        const int wsel = (b - 2048) >> 10;
        switch (wsel) {
            case 0: s = Wq;  break;
            case 1: s = Wk;  break;
            case 2: s = Wv;  break;
            case 3: s = Wgv; break;
            default: s = Wgo; break;
        }
        d = Wcatb + ((size_t)wsel << 20);
        off = (size_t)((b - 2048) & 1023) * 1024;
    } else             { s = Wo; d = Wob; off = (size_t)(b - 7168) * 1024; }

    const size_t i = off + threadIdx.x * 4;
    const float4 v = *(const float4*)(s + i);
    ushort4 o;
    o.x = f2bf(v.x); o.y = f2bf(v.y); o.z = f2bf(v.z); o.w = f2bf(v.w);
    *(ushort4*)(d + i) = o;
}

// ---------------- split-K f32 GEMM for qI/kI (exact indexer path) ----------------
// part[which][s][2048][128]; grid (2, 8, 16)
__global__ __launch_bounds__(256) void qik_splitk_kernel(
    const float* __restrict__ x, const float* __restrict__ WIq, const float* __restrict__ WIk,
    float* __restrict__ part)
{
    const int which = blockIdx.x;
    const int s = blockIdx.y;
    const int mt = blockIdx.z;
    const float* B = which ? WIk : WIq;
    const int m0 = mt * 128;
    const int kb = s * 128;

    __shared__ float As[16][132];
    __shared__ float Bs[16][132];
    const int tid = threadIdx.x;
    const int tx = tid & 15, ty = tid >> 4;

    float acc[8][8];
#pragma unroll
    for (int i = 0; i < 8; ++i)
#pragma unroll
        for (int j = 0; j < 8; ++j) acc[i][j] = 0.f;

    const int sr = tid >> 1;
    const int sk = (tid & 1) * 8;
    const float* Ap = x + (size_t)(m0 + sr) * C_DIM + kb + sk;
    const float* Bp = B + (size_t)sr * C_DIM + kb + sk;

    for (int k0 = 0; k0 < 128; k0 += 16) {
        float4 a0 = *(const float4*)(Ap + k0);
        float4 a1 = *(const float4*)(Ap + k0 + 4);
        float4 b0 = *(const float4*)(Bp + k0);
        float4 b1 = *(const float4*)(Bp + k0 + 4);
        __syncthreads();
        As[sk + 0][sr] = a0.x; As[sk + 1][sr] = a0.y; As[sk + 2][sr] = a0.z; As[sk + 3][sr] = a0.w;
        As[sk + 4][sr] = a1.x; As[sk + 5][sr] = a1.y; As[sk + 6][sr] = a1.z; As[sk + 7][sr] = a1.w;
        Bs[sk + 0][sr] = b0.x; Bs[sk + 1][sr] = b0.y; Bs[sk + 2][sr] = b0.z; Bs[sk + 3][sr] = b0.w;
        Bs[sk + 4][sr] = b1.x; Bs[sk + 5][sr] = b1.y; Bs[sk + 6][sr] = b1.z; Bs[sk + 7][sr] = b1.w;
        __syncthreads();
#pragma unroll
        for (int kk = 0; kk < 16; ++kk) {
            float4 aA = *(const float4*)&As[kk][ty * 4];
            float4 aB = *(const float4*)&As[kk][64 + ty * 4];
            float4 bA = *(const float4*)&Bs[kk][tx * 4];
            float4 bB = *(const float4*)&Bs[kk][64 + tx * 4];
            float am[8] = {aA.x, aA.y, aA.z, aA.w, aB.x, aB.y, aB.z, aB.w};
            float bn[8] = {bA.x, bA.y, bA.z, bA.w, bB.x, bB.y, bB.z, bB.w};
#pragma unroll
            for (int i = 0; i < 8; ++i)
#pragma unroll
                for (int j = 0; j < 8; ++j) acc[i][j] = fmaf(am[i], bn[j], acc[i][j]);
        }
    }

    float* cp0 = part + (size_t)(which * 8 + s) * T_SEQ * 128;
#pragma unroll
    for (int ih = 0; ih < 2; ++ih)
#pragma unroll
        for (int i = 0; i < 4; ++i) {
            const int row = m0 + ih * 64 + ty * 4 + i;
            float* cp = cp0 + (size_t)row * 128;
            float4 v0 = make_float4(acc[ih*4+i][0], acc[ih*4+i][1], acc[ih*4+i][2], acc[ih*4+i][3]);
            float4 v1 = make_float4(acc[ih*4+i][4], acc[ih*4+i][5], acc[ih*4+i][6], acc[ih*4+i][7]);
            *(float4*)(cp + tx * 4) = v0;
            *(float4*)(cp + 64 + tx * 4) = v1;
        }
}

__global__ void qik_reduce_kernel(const float* __restrict__ part,
                                  float* __restrict__ qI, float* __restrict__ kI)
{
    const int idx = blockIdx.x * 256 + threadIdx.x;   // 0..524287
    const int which = idx >> 18;
    const int e = idx & 262143;
    const float* p = part + (size_t)which * 8 * T_SEQ * 128 + e;
    float s = 0.f;
#pragma unroll
    for (int j = 0; j < 8; ++j) s += p[(size_t)j * T_SEQ * 128];
    (which ? kI : qI)[e] = s;
}

// w = sigmoid(x @ W_Iw^T), 4 threads per output
__global__ void proj_w_kernel(const float* __restrict__ x, const float* __restrict__ WIw,
                              float* __restrict__ wsig)
{
    const int idx4 = blockIdx.x * 256 + threadIdx.x;
    const int part = idx4 & 3;
    const int oidx = idx4 >> 2;      // t*4 + hi
    const int t = oidx >> 2, hi = oidx & 3;
    const float4* xr = (const float4*)(x + (size_t)t * C_DIM + part * 256);
    const float4* wr = (const float4*)(WIw + (size_t)hi * C_DIM + part * 256);
    float s = 0.f;
#pragma unroll
    for (int i = 0; i < 64; ++i) {
        float4 a = xr[i], b = wr[i];
        s += a.x * b.x + a.y * b.y + a.z * b.z + a.w * b.w;
    }
    s += __shfl_xor(s, 1);
    s += __shfl_xor(s, 2);
    if (part == 0) wsig[oidx] = sigf(s);
}

__global__ void rope_table_kernel(float* __restrict__ cost, float* __restrict__ sint)
{
    const int idx = blockIdx.x * 256 + threadIdx.x;   // t*32 + i
    const int t = idx >> 5, i = idx & 31;
    const int j = (2 * i) & 31;
    const double invd = pow(10000.0, -(double)j / 32.0);
    const float invf = (float)invd;
    const float f = (float)t * invf;
    cost[idx] = (float)cos((double)f);
    sint[idx] = (float)sin((double)f);
}

// RoPE + v*sig(gv) + extract pre-sigmoided go gate
__global__ void rope_v_kernel(
    const float* __restrict__ lincat,
    const float* __restrict__ cost, const float* __restrict__ sint,
    float* __restrict__ Q, float* __restrict__ K, float* __restrict__ V,
    float* __restrict__ gosep)
{
    const int idx = blockIdx.x * 256 + threadIdx.x;   // (t*16+h)*32 + i
    const int i = idx & 31;
    const int h = (idx >> 5) & 15;
    const int t = idx >> 9;
    const float cv = cost[t * 32 + i], sv = sint[t * 32 + i];
    const size_t src = (size_t)t * NCAT + h * HD + 2 * i;
    const float2 q2 = *(const float2*)(lincat + src);
    const float2 k2 = *(const float2*)(lincat + src + 1024);
    const float2 v2 = *(const float2*)(lincat + src + 2048);
    const float2 g2 = *(const float2*)(lincat + src + 3072);
    const float2 o2 = *(const float2*)(lincat + src + 4096);
    const size_t dst = ((size_t)h * T_SEQ + t) * HD;
    Q[dst + i]      = q2.x * cv - q2.y * sv;
    Q[dst + 32 + i] = q2.x * sv + q2.y * cv;
    K[dst + i]      = k2.x * cv - k2.y * sv;
    K[dst + 32 + i] = k2.x * sv + k2.y * cv;
    float2 vo;
    vo.x = v2.x * sigf(g2.x);
    vo.y = v2.y * sigf(g2.y);
    *(float2*)(V + dst + 2 * i) = vo;
    float2 gs;
    gs.x = sigf(o2.x);
    gs.y = sigf(o2.y);
    *(float2*)(gosep + (size_t)t * C_DIM + h * HD + 2 * i) = gs;
}

// ---------------- impA: causal-tiled f32 GEMM -> imp = wr * sigmoid(dot + gb) ----------
// grid (136, 2): triangular tile id, hi slot. imp[slot][2048][2048]
__global__ __launch_bounds__(256) void impA_kernel(
    const float* __restrict__ qI, const float* __restrict__ kI,
    const float* __restrict__ wsig, const float* __restrict__ gate_bias,
    float* __restrict__ imp, int hi_base)
{
    const int t = blockIdx.x;
    const int slot = blockIdx.y;
    const int hi = hi_base + slot;
    int qi = (int)((sqrtf(8.f * (float)t + 1.f) - 1.f) * 0.5f);
    if ((qi + 1) * (qi + 2) / 2 <= t) qi++;
    if (qi * (qi + 1) / 2 > t) qi--;
    const int ki = t - qi * (qi + 1) / 2;
    const int m0 = qi * 128, n0 = ki * 128;

    __shared__ float As[32][132];
    __shared__ float Bs[32][132];
    const int tid = threadIdx.x;
    const int tx = tid & 15, ty = tid >> 4;

    {
        const int sr = tid >> 1;
        const int sk = (tid & 1) * 16;
        const float4* Ap = (const float4*)(qI + (size_t)(m0 + sr) * 128 + hi * 32 + sk);
        const float4* Bp = (const float4*)(kI + (size_t)(n0 + sr) * 128 + hi * 32 + sk);
#pragma unroll
        for (int j4 = 0; j4 < 4; ++j4) {
            float4 a = Ap[j4], b = Bp[j4];
            As[sk + j4*4 + 0][sr] = a.x; As[sk + j4*4 + 1][sr] = a.y;
            As[sk + j4*4 + 2][sr] = a.z; As[sk + j4*4 + 3][sr] = a.w;
            Bs[sk + j4*4 + 0][sr] = b.x; Bs[sk + j4*4 + 1][sr] = b.y;
            Bs[sk + j4*4 + 2][sr] = b.z; Bs[sk + j4*4 + 3][sr] = b.w;
        }
    }
    __syncthreads();

    float acc[8][8];
#pragma unroll
    for (int i = 0; i < 8; ++i)
#pragma unroll
        for (int j = 0; j < 8; ++j) acc[i][j] = 0.f;

#pragma unroll
    for (int kk = 0; kk < 32; ++kk) {
        float4 aA = *(const float4*)&As[kk][ty * 4];
        float4 aB = *(const float4*)&As[kk][64 + ty * 4];
        float4 bA = *(const float4*)&Bs[kk][tx * 4];
        float4 bB = *(const float4*)&Bs[kk][64 + tx * 4];
        float am[8] = {aA.x, aA.y, aA.z, aA.w, aB.x, aB.y, aB.z, aB.w};
        float bn[8] = {bA.x, bA.y, bA.z, bA.w, bB.x, bB.y, bB.z, bB.w};
#pragma unroll
        for (int i = 0; i < 8; ++i)
#pragma unroll
            for (int j = 0; j < 8; ++j) acc[i][j] = fmaf(am[i], bn[j], acc[i][j]);
    }

    const float gb = gate_bias[hi];
    float* impb = imp + (size_t)slot * T_SEQ * T_SEQ;
#pragma unroll
    for (int ih = 0; ih < 2; ++ih)
#pragma unroll
        for (int i = 0; i < 4; ++i) {
            const int row = m0 + ih * 64 + ty * 4 + i;
            const float wr = wsig[row * 4 + hi];
            float* cp = impb + (size_t)row * T_SEQ + n0;
            float4 v0, v1;
            v0.x = wr * sigf(acc[ih*4+i][0] + gb);
            v0.y = wr * sigf(acc[ih*4+i][1] + gb);
            v0.z = wr * sigf(acc[ih*4+i][2] + gb);
            v0.w = wr * sigf(acc[ih*4+i][3] + gb);
            v1.x = wr * sigf(acc[ih*4+i][4] + gb);
            v1.y = wr * sigf(acc[ih*4+i][5] + gb);
            v1.z = wr * sigf(acc[ih*4+i][6] + gb);
            v1.w = wr * sigf(acc[ih*4+i][7] + gb);
            *(float4*)(cp + tx * 4) = v0;
            *(float4*)(cp + 64 + tx * 4) = v1;
        }
}

// ---------------- impB: var -> k_t, radix-select, emission -------------------
// grid (512, 2): one wave per (q, hi). Reads imp rows (coalesced).
__global__ __launch_bounds__(256) void impB_kernel(
    const float* __restrict__ imp, const float* __restrict__ head_bias,
    unsigned short* __restrict__ sidxg, unsigned* __restrict__ cnts, int hi_base)
{
    const int wv = threadIdx.x >> 6;
    const int lane = threadIdx.x & 63;
    const int q = blockIdx.x * 4 + wv;
    const int slot = blockIdx.y;
    const int hi = hi_base + slot;
    const unsigned long long lmask_lt = (lane == 0) ? 0ull : ((~0ull) >> (64 - lane));

    const float* row = imp + (size_t)slot * T_SEQ * T_SEQ + (size_t)q * T_SEQ;

    unsigned ordv[32];
    double dsum = 0.0, dsq = 0.0;
#pragma unroll
    for (int i = 0; i < 32; ++i) {
        const int k = i * 64 + lane;
        const float v = row[k];
        const bool causal = (k <= q);
        const float vm = causal ? v : 0.f;
        dsum += (double)vm;
        dsq  += (double)vm * (double)vm;
        unsigned vb = causal ? __float_as_uint(v) : 0u;
        if (k < SINKN) vb = 0x7F800000u;
        ordv[i] = vb;
    }

#pragma unroll
    for (int off = 1; off < 64; off <<= 1) {
        dsum += __shfl_xor(dsum, off);
        dsq  += __shfl_xor(dsq, off);
    }

    int kts[4];
#pragma unroll
    for (int j = 0; j < 4; ++j) {
        const float sh = sigf(head_bias[hi * 4 + j]);
        const double mean = dsum / (double)T_SEQ;
        double var = dsq / (double)T_SEQ - mean * mean;
        if (var < 0.0) var = 0.0;
        const double vh = var * (double)sh * (double)sh;
        int kt = (int)floor(512.0 * vh);
        kt = kt < KMINV ? KMINV : (kt > KMAXV ? KMAXV : kt);
        kts[j] = kt;
    }

    unsigned vs[4]; int tt[4];
#pragma unroll
    for (int j = 0; j < 4; ++j) {
        bool dup = false;
#pragma unroll
        for (int p = 0; p < 4; ++p) {
            if (p < j && !dup && kts[p] == kts[j]) { vs[j] = vs[p]; tt[j] = tt[p]; dup = true; }
        }
        if (!dup) {
            unsigned P = 0; int Kp = kts[j];
#pragma unroll 1
            for (int b = 30; b >= 0; --b) {
                const unsigned cand = (P >> b) | 1u;
                int c = 0;
#pragma unroll
                for (int i = 0; i < 32; ++i) c += ((ordv[i] >> b) == cand) ? 1 : 0;
#pragma unroll
                for (int off = 1; off < 64; off <<= 1) c += __shfl_xor(c, off);
                if (c >= Kp) P |= (1u << b);
                else Kp -= c;
            }
            vs[j] = P; tt[j] = Kp;
        }
    }

    unsigned cnt = 0;
    unsigned short* sp = sidxg + ((size_t)hi * T_SEQ + q) * KMAXV;
    const bool uni = (kts[0] == kts[1]) && (kts[1] == kts[2]) && (kts[2] == kts[3]);

    if (uni) {
        int eqr = 0;
        const unsigned v0 = vs[0]; const int t0 = tt[0];
#pragma unroll
        for (int i = 0; i < 32; ++i) {
            const int k = i * 64 + lane;
            const unsigned x = ordv[i];
            const bool eq = (x == v0);
            const unsigned long long beq = __ballot(eq);
            const bool sel = (x > v0) || (eq && (eqr + (int)__popcll(beq & lmask_lt) < t0));
            eqr += (int)__popcll(beq);
            const bool valid = (k <= q) && sel;
            const unsigned long long bv = __ballot(valid);
            if (valid) {
                const unsigned pos = cnt + (unsigned)__popcll(bv & lmask_lt);
                sp[pos] = (unsigned short)((unsigned)k | (0xFu << 11));
            }
            cnt += (unsigned)__popcll(bv);
        }
    } else {
        int eqr0 = 0, eqr1 = 0, eqr2 = 0, eqr3 = 0;
#pragma unroll
        for (int i = 0; i < 32; ++i) {
            const int k = i * 64 + lane;
            const unsigned x = ordv[i];
            unsigned mask = 0;
            {
                const bool eq = (x == vs[0]);
                const unsigned long long beq = __ballot(eq);
                const bool sel = (x > vs[0]) || (eq && (eqr0 + (int)__popcll(beq & lmask_lt) < tt[0]));
                eqr0 += (int)__popcll(beq);
                if (sel) mask |= 1u;
            }
            {
                const bool eq = (x == vs[1]);
                const unsigned long long beq = __ballot(eq);
                const bool sel = (x > vs[1]) || (eq && (eqr1 + (int)__popcll(beq & lmask_lt) < tt[1]));
                eqr1 += (int)__popcll(beq);
                if (sel) mask |= 2u;
            }
            {
                const bool eq = (x == vs[2]);
                const unsigned long long beq = __ballot(eq);
                const bool sel = (x > vs[2]) || (eq && (eqr2 + (int)__popcll(beq & lmask_lt) < tt[2]));
                eqr2 += (int)__popcll(beq);
                if (sel) mask |= 4u;
            }
            {
                const bool eq = (x == vs[3]);
                const unsigned long long beq = __ballot(eq);
                const bool sel = (x > vs[3]) || (eq && (eqr3 + (int)__popcll(beq & lmask_lt) < tt[3]));
                eqr3 += (int)__popcll(beq);
                if (sel) mask |= 8u;
            }
            const bool valid = (k <= q) && (mask != 0u);
            const unsigned long long bv = __ballot(valid);
            if (valid) {
                const unsigned pos = cnt + (unsigned)__popcll(bv & lmask_lt);
                sp[pos] = (unsigned short)((unsigned)k | (mask << 11));
            }
            cnt += (unsigned)__popcll(bv);
        }
    }
    if (lane == 0) cnts[(size_t)hi * T_SEQ + q] = cnt;
}

// sparse gather attention + fused output gate; writes bf16 og directly
__global__ __launch_bounds__(256) void attn_sparse_kernel(
    const float* __restrict__ Q, const float* __restrict__ K, const float* __restrict__ V,
    const unsigned short* __restrict__ sidx, const unsigned* __restrict__ cnts,
    const float* __restrict__ gosep, unsigned short* __restrict__ ogb)
{
    const int h  = blockIdx.y;
    const int hi = h >> 2, hj = h & 3;
    const int wv = threadIdx.x >> 6;
    const int lane = threadIdx.x & 63;
    const int q = blockIdx.x * 4 + wv;

    const size_t hq = (size_t)hi * T_SEQ + q;
    const int nv = (int)cnts[hq];

    const float qd = Q[((size_t)h * T_SEQ + q) * HD + lane];  // lane = dim
    const unsigned short* sp = sidx + hq * KMAXV;
    const float* Kh = K + (size_t)h * T_SEQ * HD;
    const float* Vh = V + (size_t)h * T_SEQ * HD;

    float m = -INFINITY, l = 0.f, o = 0.f;

    for (int base = 0; base < nv; base += 64) {
        const int nk = min(64, nv - base);
        const unsigned e = (lane < nk) ? (unsigned)sp[base + lane] : 0u;
        const int idxv = (int)(e & 0x7FFu);
        const bool ok = (lane < nk) && ((e >> (11 + hj)) & 1u);
        const unsigned long long bvok = __ballot(ok);

        const float4* kr = (const float4*)(Kh + (size_t)idxv * HD);
        float acc = 0.f;
#pragma unroll
        for (int d4 = 0; d4 < 16; ++d4) {
            float4 kv = kr[d4];
            acc = fmaf(__shfl(qd, d4 * 4 + 0), kv.x, acc);
            acc = fmaf(__shfl(qd, d4 * 4 + 1), kv.y, acc);
            acc = fmaf(__shfl(qd, d4 * 4 + 2), kv.z, acc);
            acc = fmaf(__shfl(qd, d4 * 4 + 3), kv.w, acc);
        }
        float s = ok ? acc * 0.125f : -INFINITY;

        float cm = s;
#pragma unroll
        for (int off = 32; off > 0; off >>= 1) cm = fmaxf(cm, __shfl_xor(cm, off));
        const float mn = fmaxf(m, cm);
        if (mn > -INFINITY) {
            const float alpha = expf(m - mn);
            const float p = expf(s - mn);
            float ls = p;
#pragma unroll
            for (int off = 32; off > 0; off >>= 1) ls += __shfl_xor(ls, off);
            l = l * alpha + ls;
            o = o * alpha;
            unsigned long long bb = bvok;
            while (bb) {
                const int k = (int)__ffsll((long long)bb) - 1;
                bb &= bb - 1;
                const float pk = __shfl(p, k);
                const int iv = __shfl(idxv, k);
                o = fmaf(pk, Vh[(size_t)iv * HD + lane], o);
            }
            m = mn;
        }
    }
    const float invl = 1.f / l;
    const float gs = gosep[(size_t)q * C_DIM + h * HD + lane];
    ogb[(size_t)q * C_DIM + h * HD + lane] = f2bf(o * invl * gs);
}

extern "C" void kernel_launch(void* const* d_in, const int* in_sizes, int n_in,
                              void* d_out, int out_size, void* d_ws, size_t ws_size,
                              hipStream_t stream)
{
    const float* x   = (const float*)d_in[0];
    const float* WIq = (const float*)d_in[1];
    const float* WIk = (const float*)d_in[2];
    const float* WIw = (const float*)d_in[3];
    const float* gb  = (const float*)d_in[4];
    const float* hib = (const float*)d_in[5];
    const float* Wq  = (const float*)d_in[6];
    const float* Wk  = (const float*)d_in[7];
    const float* Wv  = (const float*)d_in[8];
    const float* Wgv = (const float*)d_in[9];
    const float* Wgo = (const float*)d_in[10];
    const float* Wo  = (const float*)d_in[11];
    float* out = (float*)d_out;

    char* ws = (char*)d_ws;
    const size_t MB = 1024 * 1024;
    float*    qI     = (float*)(ws + 0 * MB);                 // 1 MB
    float*    kI     = (float*)(ws + 1 * MB);                 // 1 MB
    float*    wsig   = (float*)(ws + 2 * MB);                 // 32 KB
    unsigned* cnts   = (unsigned*)(ws + 2 * MB + 64 * 1024);  // 32 KB
    float*    cost   = (float*)(ws + 2 * MB + 512 * 1024);    // 256 KB
    float*    sint   = (float*)(ws + 2 * MB + 768 * 1024);    // 256 KB
    float*    gosep  = (float*)(ws + 3 * MB);                 // 8 MB  -> 11
    float*    Q      = (float*)(ws + 11 * MB);                // 8 MB  -> 19
    float*    K      = (float*)(ws + 19 * MB);                // 8 MB  -> 27
    float*    V      = (float*)(ws + 27 * MB);                // 8 MB  -> 35
    unsigned short* sidx = (unsigned short*)(ws + 35 * MB);   // 16 MB -> 51
    // region A (51..91): qik partials (16) -> imp (32, 2 hi at a time) -> lincat (40)
    float*    part   = (float*)(ws + 51 * MB);
    float*    imp    = (float*)(ws + 51 * MB);
    float*    lincat = (float*)(ws + 51 * MB);
    unsigned short* ogb   = (unsigned short*)(ws + 91 * MB);  // 4 MB  -> 95
    unsigned short* xb    = (unsigned short*)(ws + 95 * MB);  // 4 MB  -> 99
    unsigned short* Wcatb = (unsigned short*)(ws + 99 * MB);  // 10 MB -> 109
    unsigned short* Wob   = (unsigned short*)(ws + 109 * MB); // 2 MB  -> 111

    rope_table_kernel<<<dim3(256), 256, 0, stream>>>(cost, sint);
    qik_splitk_kernel<<<dim3(2, 8, 16), 256, 0, stream>>>(x, WIq, WIk, part);
    qik_reduce_kernel<<<dim3(2048), 256, 0, stream>>>(part, qI, kI);
    proj_w_kernel<<<dim3(128), 256, 0, stream>>>(x, WIw, wsig);
    for (int h2 = 0; h2 < 2; ++h2) {
        impA_kernel<<<dim3(136, 2), 256, 0, stream>>>(qI, kI, wsig, gb, imp, h2 * 2);
        impB_kernel<<<dim3(512, 2), 256, 0, stream>>>(imp, hib, sidx, cnts, h2 * 2);
    }
    convert_all_kernel<<<dim3(8192), 256, 0, stream>>>(
        x, Wq, Wk, Wv, Wgv, Wgo, Wo, xb, Wcatb, Wob);
    gemm_bf16_kernel<<<dim3(40, 16), 256, 0, stream>>>(xb, Wcatb, lincat, NCAT);
    rope_v_kernel<<<dim3(4096), 256, 0, stream>>>(lincat, cost, sint, Q, K, V, gosep);
    attn_sparse_kernel<<<dim3(512, 16), 256, 0, stream>>>(Q, K, V, sidx, cnts, gosep, ogb);
    gemm_bf16_kernel<<<dim3(8, 16), 256, 0, stream>>>(ogb, Wob, out, C_DIM);
}

// Round 6
// 300.635 us; speedup vs baseline: 5.2565x; 1.0785x over previous
//
#include <hip/hip_runtime.h>
#include <math.h>

#define T_SEQ 2048
#define C_DIM 1024
#define NH    16
#define HD    64
#define HIN   4
#define DI    32
#define SINKN 4
#define KMINV 32
#define KMAXV 1024
#define NCAT  5120   // q|k|v|gv|go concatenated columns

typedef __bf16 bf16x8 __attribute__((ext_vector_type(8)));
typedef float  f32x4  __attribute__((ext_vector_type(4)));

__device__ __forceinline__ float sigf(float x) { return 1.f / (1.f + expf(-x)); }

__device__ __forceinline__ unsigned short f2bf(float f) {
    unsigned u = __float_as_uint(f);
    unsigned r = (u + 0x7FFFu + ((u >> 16) & 1u)) >> 16;   // RNE
    return (unsigned short)r;
}

__device__ __forceinline__ void gload16(const unsigned short* g, unsigned short* l) {
    __builtin_amdgcn_global_load_lds(
        (const __attribute__((address_space(1))) unsigned int*)(const unsigned int*)g,
        (__attribute__((address_space(3))) unsigned int*)(unsigned int*)l,
        16, 0, 0);
}

// ---------------- bf16 MFMA GEMM: C(f32) = A_bf16 @ B_bf16^T ----------------
__global__ __launch_bounds__(256) void gemm_bf16_kernel(
    const unsigned short* __restrict__ A, const unsigned short* __restrict__ B,
    float* __restrict__ C, int ldc)
{
    __shared__ unsigned short Asl[128 * 64];
    __shared__ unsigned short Bsl[128 * 64];
    const int K = C_DIM;
    const int tid = threadIdx.x;
    const int w = tid >> 6, lane = tid & 63;
    const int wm = w >> 1, wn = w & 1;
    const int m0 = blockIdx.y * 128, n0 = blockIdx.x * 128;

    const f32x4 z4 = {0.f, 0.f, 0.f, 0.f};
    f32x4 acc[4][4];
#pragma unroll
    for (int i = 0; i < 4; ++i)
#pragma unroll
        for (int j = 0; j < 4; ++j) acc[i][j] = z4;

    const int lrow  = w * 8 + (lane >> 3);
    const int lslot = (lane & 7) ^ (lane >> 3);
    const unsigned short* Ag = A + (size_t)(m0 + lrow) * K + lslot * 8;
    const unsigned short* Bg = B + (size_t)(n0 + lrow) * K + lslot * 8;

    const int fr = lane & 15;
    const int kg = lane >> 4;

    for (int kt = 0; kt < K; kt += 64) {
        __syncthreads();
#pragma unroll
        for (int i = 0; i < 4; ++i) {
            gload16(Ag + (size_t)(i * 32) * K + kt, &Asl[(i * 32 + w * 8) * 64]);
            gload16(Bg + (size_t)(i * 32) * K + kt, &Bsl[(i * 32 + w * 8) * 64]);
        }
        __syncthreads();
#pragma unroll
        for (int ks = 0; ks < 2; ++ks) {
            bf16x8 af[4], bfr[4];
            const int aslot = ks * 4 + kg;
#pragma unroll
            for (int f = 0; f < 4; ++f) {
                const int arow = wm * 64 + f * 16 + fr;
                af[f] = *(const bf16x8*)&Asl[arow * 64 + ((aslot ^ (arow & 7)) * 8)];
                const int brow = wn * 64 + f * 16 + fr;
                bfr[f] = *(const bf16x8*)&Bsl[brow * 64 + ((aslot ^ (brow & 7)) * 8)];
            }
#pragma unroll
            for (int mi = 0; mi < 4; ++mi)
#pragma unroll
                for (int ni = 0; ni < 4; ++ni)
                    acc[mi][ni] = __builtin_amdgcn_mfma_f32_16x16x32_bf16(
                        af[mi], bfr[ni], acc[mi][ni], 0, 0, 0);
        }
    }

#pragma unroll
    for (int mi = 0; mi < 4; ++mi) {
        const int row = m0 + wm * 64 + mi * 16 + (lane >> 4) * 4;
#pragma unroll
        for (int ni = 0; ni < 4; ++ni) {
            const int col = n0 + wn * 64 + ni * 16 + (lane & 15);
            float* cp = C + (size_t)row * ldc + col;
#pragma unroll
            for (int r = 0; r < 4; ++r) cp[(size_t)r * ldc] = acc[mi][ni][r];
        }
    }
}

// one-shot f32 -> bf16 conversion of x and all big weights
__global__ __launch_bounds__(256) void convert_all_kernel(
    const float* __restrict__ x,
    const float* __restrict__ Wq, const float* __restrict__ Wk, const float* __restrict__ Wv,
    const float* __restrict__ Wgv, const float* __restrict__ Wgo, const float* __restrict__ Wo,
    unsigned short* __restrict__ xb, unsigned short* __restrict__ Wcatb,
    unsigned short* __restrict__ Wob)
{
    const int b = blockIdx.x;
    const float* s; unsigned short* d; size_t off;
    if (b < 2048)      { s = x;  d = xb;  off = (size_t)b * 1024; }
    else if (b < 7168) {
        const int wsel = (b - 2048) >> 10;
        switch (wsel) {
            case 0: s = Wq;  break;
            case 1: s = Wk;  break;
            case 2: s = Wv;  break;
            case 3: s = Wgv; break;
            default: s = Wgo; break;
        }
        d = Wcatb + ((size_t)wsel << 20);
        off = (size_t)((b - 2048) & 1023) * 1024;
    } else             { s = Wo; d = Wob; off = (size_t)(b - 7168) * 1024; }

    const size_t i = off + threadIdx.x * 4;
    const float4 v = *(const float4*)(s + i);
    ushort4 o;
    o.x = f2bf(v.x); o.y = f2bf(v.y); o.z = f2bf(v.z); o.w = f2bf(v.w);
    *(ushort4*)(d + i) = o;
}

// ---------------- split-K f32 GEMM for qI/kI (exact indexer path) ----------------
__global__ __launch_bounds__(256) void qik_splitk_kernel(
    const float* __restrict__ x, const float* __restrict__ WIq, const float* __restrict__ WIk,
    float* __restrict__ part)
{
    const int which = blockIdx.x;
    const int s = blockIdx.y;
    const int mt = blockIdx.z;
    const float* B = which ? WIk : WIq;
    const int m0 = mt * 128;
    const int kb = s * 128;

    __shared__ float As[16][132];
    __shared__ float Bs[16][132];
    const int tid = threadIdx.x;
    const int tx = tid & 15, ty = tid >> 4;

    float acc[8][8];
#pragma unroll
    for (int i = 0; i < 8; ++i)
#pragma unroll
        for (int j = 0; j < 8; ++j) acc[i][j] = 0.f;

    const int sr = tid >> 1;
    const int sk = (tid & 1) * 8;
    const float* Ap = x + (size_t)(m0 + sr) * C_DIM + kb + sk;
    const float* Bp = B + (size_t)sr * C_DIM + kb + sk;

    for (int k0 = 0; k0 < 128; k0 += 16) {
        float4 a0 = *(const float4*)(Ap + k0);
        float4 a1 = *(const float4*)(Ap + k0 + 4);
        float4 b0 = *(const float4*)(Bp + k0);
        float4 b1 = *(const float4*)(Bp + k0 + 4);
        __syncthreads();
        As[sk + 0][sr] = a0.x; As[sk + 1][sr] = a0.y; As[sk + 2][sr] = a0.z; As[sk + 3][sr] = a0.w;
        As[sk + 4][sr] = a1.x; As[sk + 5][sr] = a1.y; As[sk + 6][sr] = a1.z; As[sk + 7][sr] = a1.w;
        Bs[sk + 0][sr] = b0.x; Bs[sk + 1][sr] = b0.y; Bs[sk + 2][sr] = b0.z; Bs[sk + 3][sr] = b0.w;
        Bs[sk + 4][sr] = b1.x; Bs[sk + 5][sr] = b1.y; Bs[sk + 6][sr] = b1.z; Bs[sk + 7][sr] = b1.w;
        __syncthreads();
#pragma unroll
        for (int kk = 0; kk < 16; ++kk) {
            float4 aA = *(const float4*)&As[kk][ty * 4];
            float4 aB = *(const float4*)&As[kk][64 + ty * 4];
            float4 bA = *(const float4*)&Bs[kk][tx * 4];
            float4 bB = *(const float4*)&Bs[kk][64 + tx * 4];
            float am[8] = {aA.x, aA.y, aA.z, aA.w, aB.x, aB.y, aB.z, aB.w};
            float bn[8] = {bA.x, bA.y, bA.z, bA.w, bB.x, bB.y, bB.z, bB.w};
#pragma unroll
            for (int i = 0; i < 8; ++i)
#pragma unroll
                for (int j = 0; j < 8; ++j) acc[i][j] = fmaf(am[i], bn[j], acc[i][j]);
        }
    }

    float* cp0 = part + (size_t)(which * 8 + s) * T_SEQ * 128;
#pragma unroll
    for (int ih = 0; ih < 2; ++ih)
#pragma unroll
        for (int i = 0; i < 4; ++i) {
            const int row = m0 + ih * 64 + ty * 4 + i;
            float* cp = cp0 + (size_t)row * 128;
            float4 v0 = make_float4(acc[ih*4+i][0], acc[ih*4+i][1], acc[ih*4+i][2], acc[ih*4+i][3]);
            float4 v1 = make_float4(acc[ih*4+i][4], acc[ih*4+i][5], acc[ih*4+i][6], acc[ih*4+i][7]);
            *(float4*)(cp + tx * 4) = v0;
            *(float4*)(cp + 64 + tx * 4) = v1;
        }
}

__global__ void qik_reduce_kernel(const float* __restrict__ part,
                                  float* __restrict__ qI, float* __restrict__ kI)
{
    const int idx = blockIdx.x * 256 + threadIdx.x;   // 0..524287
    const int which = idx >> 18;
    const int e = idx & 262143;
    const float* p = part + (size_t)which * 8 * T_SEQ * 128 + e;
    float s = 0.f;
#pragma unroll
    for (int j = 0; j < 8; ++j) s += p[(size_t)j * T_SEQ * 128];
    (which ? kI : qI)[e] = s;
}

// w = sigmoid(x @ W_Iw^T), 4 threads per output
__global__ void proj_w_kernel(const float* __restrict__ x, const float* __restrict__ WIw,
                              float* __restrict__ wsig)
{
    const int idx4 = blockIdx.x * 256 + threadIdx.x;
    const int part = idx4 & 3;
    const int oidx = idx4 >> 2;      // t*4 + hi
    const int t = oidx >> 2, hi = oidx & 3;
    const float4* xr = (const float4*)(x + (size_t)t * C_DIM + part * 256);
    const float4* wr = (const float4*)(WIw + (size_t)hi * C_DIM + part * 256);
    float s = 0.f;
#pragma unroll
    for (int i = 0; i < 64; ++i) {
        float4 a = xr[i], b = wr[i];
        s += a.x * b.x + a.y * b.y + a.z * b.z + a.w * b.w;
    }
    s += __shfl_xor(s, 1);
    s += __shfl_xor(s, 2);
    if (part == 0) wsig[oidx] = sigf(s);
}

__global__ void rope_table_kernel(float* __restrict__ cost, float* __restrict__ sint)
{
    const int idx = blockIdx.x * 256 + threadIdx.x;   // t*32 + i
    const int t = idx >> 5, i = idx & 31;
    const int j = (2 * i) & 31;
    const double invd = pow(10000.0, -(double)j / 32.0);
    const float invf = (float)invd;
    const float f = (float)t * invf;
    cost[idx] = (float)cos((double)f);
    sint[idx] = (float)sin((double)f);
}

// RoPE + v*sig(gv) + extract pre-sigmoided go gate
__global__ void rope_v_kernel(
    const float* __restrict__ lincat,
    const float* __restrict__ cost, const float* __restrict__ sint,
    float* __restrict__ Q, float* __restrict__ K, float* __restrict__ V,
    float* __restrict__ gosep)
{
    const int idx = blockIdx.x * 256 + threadIdx.x;   // (t*16+h)*32 + i
    const int i = idx & 31;
    const int h = (idx >> 5) & 15;
    const int t = idx >> 9;
    const float cv = cost[t * 32 + i], sv = sint[t * 32 + i];
    const size_t src = (size_t)t * NCAT + h * HD + 2 * i;
    const float2 q2 = *(const float2*)(lincat + src);
    const float2 k2 = *(const float2*)(lincat + src + 1024);
    const float2 v2 = *(const float2*)(lincat + src + 2048);
    const float2 g2 = *(const float2*)(lincat + src + 3072);
    const float2 o2 = *(const float2*)(lincat + src + 4096);
    const size_t dst = ((size_t)h * T_SEQ + t) * HD;
    Q[dst + i]      = q2.x * cv - q2.y * sv;
    Q[dst + 32 + i] = q2.x * sv + q2.y * cv;
    K[dst + i]      = k2.x * cv - k2.y * sv;
    K[dst + 32 + i] = k2.x * sv + k2.y * cv;
    float2 vo;
    vo.x = v2.x * sigf(g2.x);
    vo.y = v2.y * sigf(g2.y);
    *(float2*)(V + dst + 2 * i) = vo;
    float2 gs;
    gs.x = sigf(o2.x);
    gs.y = sigf(o2.y);
    *(float2*)(gosep + (size_t)t * C_DIM + h * HD + 2 * i) = gs;
}

// ---------------- impA: causal-tiled f32 GEMM -> imp = wr * sigmoid(dot + gb) ----------
__global__ __launch_bounds__(256) void impA_kernel(
    const float* __restrict__ qI, const float* __restrict__ kI,
    const float* __restrict__ wsig, const float* __restrict__ gate_bias,
    float* __restrict__ imp, int hi_base)
{
    const int t = blockIdx.x;
    const int slot = blockIdx.y;
    const int hi = hi_base + slot;
    int qi = (int)((sqrtf(8.f * (float)t + 1.f) - 1.f) * 0.5f);
    if ((qi + 1) * (qi + 2) / 2 <= t) qi++;
    if (qi * (qi + 1) / 2 > t) qi--;
    const int ki = t - qi * (qi + 1) / 2;
    const int m0 = qi * 128, n0 = ki * 128;

    __shared__ float As[32][132];
    __shared__ float Bs[32][132];
    const int tid = threadIdx.x;
    const int tx = tid & 15, ty = tid >> 4;

    {
        const int sr = tid >> 1;
        const int sk = (tid & 1) * 16;
        const float4* Ap = (const float4*)(qI + (size_t)(m0 + sr) * 128 + hi * 32 + sk);
        const float4* Bp = (const float4*)(kI + (size_t)(n0 + sr) * 128 + hi * 32 + sk);
#pragma unroll
        for (int j4 = 0; j4 < 4; ++j4) {
            float4 a = Ap[j4], b = Bp[j4];
            As[sk + j4*4 + 0][sr] = a.x; As[sk + j4*4 + 1][sr] = a.y;
            As[sk + j4*4 + 2][sr] = a.z; As[sk + j4*4 + 3][sr] = a.w;
            Bs[sk + j4*4 + 0][sr] = b.x; Bs[sk + j4*4 + 1][sr] = b.y;
            Bs[sk + j4*4 + 2][sr] = b.z; Bs[sk + j4*4 + 3][sr] = b.w;
        }
    }
    __syncthreads();

    float acc[8][8];
#pragma unroll
    for (int i = 0; i < 8; ++i)
#pragma unroll
        for (int j = 0; j < 8; ++j) acc[i][j] = 0.f;

#pragma unroll
    for (int kk = 0; kk < 32; ++kk) {
        float4 aA = *(const float4*)&As[kk][ty * 4];
        float4 aB = *(const float4*)&As[kk][64 + ty * 4];
        float4 bA = *(const float4*)&Bs[kk][tx * 4];
        float4 bB = *(const float4*)&Bs[kk][64 + tx * 4];
        float am[8] = {aA.x, aA.y, aA.z, aA.w, aB.x, aB.y, aB.z, aB.w};
        float bn[8] = {bA.x, bA.y, bA.z, bA.w, bB.x, bB.y, bB.z, bB.w};
#pragma unroll
        for (int i = 0; i < 8; ++i)
#pragma unroll
            for (int j = 0; j < 8; ++j) acc[i][j] = fmaf(am[i], bn[j], acc[i][j]);
    }

    const float gb = gate_bias[hi];
    float* impb = imp + (size_t)slot * T_SEQ * T_SEQ;
#pragma unroll
    for (int ih = 0; ih < 2; ++ih)
#pragma unroll
        for (int i = 0; i < 4; ++i) {
            const int row = m0 + ih * 64 + ty * 4 + i;
            const float wr = wsig[row * 4 + hi];
            float* cp = impb + (size_t)row * T_SEQ + n0;
            float4 v0, v1;
            v0.x = wr * sigf(acc[ih*4+i][0] + gb);
            v0.y = wr * sigf(acc[ih*4+i][1] + gb);
            v0.z = wr * sigf(acc[ih*4+i][2] + gb);
            v0.w = wr * sigf(acc[ih*4+i][3] + gb);
            v1.x = wr * sigf(acc[ih*4+i][4] + gb);
            v1.y = wr * sigf(acc[ih*4+i][5] + gb);
            v1.z = wr * sigf(acc[ih*4+i][6] + gb);
            v1.w = wr * sigf(acc[ih*4+i][7] + gb);
            *(float4*)(cp + tx * 4) = v0;
            *(float4*)(cp + 64 + tx * 4) = v1;
        }
}

// ---------------- impB: var -> k_t, radix-select, emission -------------------
__global__ __launch_bounds__(256) void impB_kernel(
    const float* __restrict__ imp, const float* __restrict__ head_bias,
    unsigned short* __restrict__ sidxg, unsigned* __restrict__ cnts, int hi_base)
{
    const int wv = threadIdx.x >> 6;
    const int lane = threadIdx.x & 63;
    const int q = blockIdx.x * 4 + wv;
    const int slot = blockIdx.y;
    const int hi = hi_base + slot;
    const unsigned long long lmask_lt = (lane == 0) ? 0ull : ((~0ull) >> (64 - lane));

    const float* row = imp + (size_t)slot * T_SEQ * T_SEQ + (size_t)q * T_SEQ;

    unsigned ordv[32];
    double dsum = 0.0, dsq = 0.0;
#pragma unroll
    for (int i = 0; i < 32; ++i) {
        const int k = i * 64 + lane;
        const float v = row[k];
        const bool causal = (k <= q);
        const float vm = causal ? v : 0.f;
        dsum += (double)vm;
        dsq  += (double)vm * (double)vm;
        unsigned vb = causal ? __float_as_uint(v) : 0u;
        if (k < SINKN) vb = 0x7F800000u;
        ordv[i] = vb;
    }

#pragma unroll
    for (int off = 1; off < 64; off <<= 1) {
        dsum += __shfl_xor(dsum, off);
        dsq  += __shfl_xor(dsq, off);
    }

    int kts[4];
#pragma unroll
    for (int j = 0; j < 4; ++j) {
        const float sh = sigf(head_bias[hi * 4 + j]);
        const double mean = dsum / (double)T_SEQ;
        double var = dsq / (double)T_SEQ - mean * mean;
        if (var < 0.0) var = 0.0;
        const double vh = var * (double)sh * (double)sh;
        int kt = (int)floor(512.0 * vh);
        kt = kt < KMINV ? KMINV : (kt > KMAXV ? KMAXV : kt);
        kts[j] = kt;
    }

    unsigned vs[4]; int tt[4];
#pragma unroll
    for (int j = 0; j < 4; ++j) {
        bool dup = false;
#pragma unroll
        for (int p = 0; p < 4; ++p) {
            if (p < j && !dup && kts[p] == kts[j]) { vs[j] = vs[p]; tt[j] = tt[p]; dup = true; }
        }
        if (!dup) {
            unsigned P = 0; int Kp = kts[j];
#pragma unroll 1
            for (int b = 30; b >= 0; --b) {
                const unsigned cand = (P >> b) | 1u;
                int c = 0;
#pragma unroll
                for (int i = 0; i < 32; ++i) c += ((ordv[i] >> b) == cand) ? 1 : 0;
#pragma unroll
                for (int off = 1; off < 64; off <<= 1) c += __shfl_xor(c, off);
                if (c >= Kp) P |= (1u << b);
                else Kp -= c;
            }
            vs[j] = P; tt[j] = Kp;
        }
    }

    unsigned cnt = 0;
    unsigned short* sp = sidxg + ((size_t)hi * T_SEQ + q) * KMAXV;
    const bool uni = (kts[0] == kts[1]) && (kts[1] == kts[2]) && (kts[2] == kts[3]);

    if (uni) {
        int eqr = 0;
        const unsigned v0 = vs[0]; const int t0 = tt[0];
#pragma unroll
        for (int i = 0; i < 32; ++i) {
            const int k = i * 64 + lane;
            const unsigned x = ordv[i];
            const bool eq = (x == v0);
            const unsigned long long beq = __ballot(eq);
            const bool sel = (x > v0) || (eq && (eqr + (int)__popcll(beq & lmask_lt) < t0));
            eqr += (int)__popcll(beq);
            const bool valid = (k <= q) && sel;
            const unsigned long long bv = __ballot(valid);
            if (valid) {
                const unsigned pos = cnt + (unsigned)__popcll(bv & lmask_lt);
                if (pos < KMAXV) sp[pos] = (unsigned short)((unsigned)k | (0xFu << 11));
            }
            cnt += (unsigned)__popcll(bv);
        }
    } else {
        int eqr0 = 0, eqr1 = 0, eqr2 = 0, eqr3 = 0;
#pragma unroll
        for (int i = 0; i < 32; ++i) {
            const int k = i * 64 + lane;
            const unsigned x = ordv[i];
            unsigned mask = 0;
            {
                const bool eq = (x == vs[0]);
                const unsigned long long beq = __ballot(eq);
                const bool sel = (x > vs[0]) || (eq && (eqr0 + (int)__popcll(beq & lmask_lt) < tt[0]));
                eqr0 += (int)__popcll(beq);
                if (sel) mask |= 1u;
            }
            {
                const bool eq = (x == vs[1]);
                const unsigned long long beq = __ballot(eq);
                const bool sel = (x > vs[1]) || (eq && (eqr1 + (int)__popcll(beq & lmask_lt) < tt[1]));
                eqr1 += (int)__popcll(beq);
                if (sel) mask |= 2u;
            }
            {
                const bool eq = (x == vs[2]);
                const unsigned long long beq = __ballot(eq);
                const bool sel = (x > vs[2]) || (eq && (eqr2 + (int)__popcll(beq & lmask_lt) < tt[2]));
                eqr2 += (int)__popcll(beq);
                if (sel) mask |= 4u;
            }
            {
                const bool eq = (x == vs[3]);
                const unsigned long long beq = __ballot(eq);
                const bool sel = (x > vs[3]) || (eq && (eqr3 + (int)__popcll(beq & lmask_lt) < tt[3]));
                eqr3 += (int)__popcll(beq);
                if (sel) mask |= 8u;
            }
            const bool valid = (k <= q) && (mask != 0u);
            const unsigned long long bv = __ballot(valid);
            if (valid) {
                const unsigned pos = cnt + (unsigned)__popcll(bv & lmask_lt);
                if (pos < KMAXV) sp[pos] = (unsigned short)((unsigned)k | (mask << 11));
            }
            cnt += (unsigned)__popcll(bv);
        }
    }
    if (lane == 0) cnts[(size_t)hi * T_SEQ + q] = cnt < KMAXV ? cnt : KMAXV;
}

// ---------------- sparse gather attention, shuffle-free hot path --------------
// lane = kk*4 + dg: key-slot kk (4 consecutive keys per chunk), dim-group dg (16 dims).
// QK: per-lane 16-dim partial dot + 2 DPP xor; softmax: xor(4..32) only; PV: lane-local.
__global__ __launch_bounds__(256) void attn_sparse_kernel(
    const float* __restrict__ Q, const float* __restrict__ K, const float* __restrict__ V,
    const unsigned short* __restrict__ sidx, const unsigned* __restrict__ cnts,
    const float* __restrict__ gosep, unsigned short* __restrict__ ogb)
{
    const int h  = blockIdx.y;
    const int hi = h >> 2, hj = h & 3;
    const int wv = threadIdx.x >> 6;
    const int lane = threadIdx.x & 63;
    const int q = blockIdx.x * 4 + wv;

    const int kk = lane >> 2;   // key slot 0..15
    const int dg = lane & 3;    // dim group 0..3

    const size_t hq = (size_t)hi * T_SEQ + q;
    const int nv = (int)cnts[hq];
    const unsigned short* sp = sidx + hq * KMAXV;
    const float* Kh = K + (size_t)h * T_SEQ * HD + dg * 16;
    const float* Vh = V + (size_t)h * T_SEQ * HD + dg * 16;

    // this lane's 16 q-dims
    float4 qg[4];
    {
        const float4* qp = (const float4*)(Q + ((size_t)h * T_SEQ + q) * HD + dg * 16);
        qg[0] = qp[0]; qg[1] = qp[1]; qg[2] = qp[2]; qg[3] = qp[3];
    }

    float acc[16];
#pragma unroll
    for (int i = 0; i < 16; ++i) acc[i] = 0.f;
    float m = -INFINITY, l = 0.f;

    for (int base = 0; base < nv; base += 64) {
        const int nk = nv - base < 64 ? nv - base : 64;
        // this lane's 4 keys: base + kk*4 + sub
        const ushort4 e4 = *(const ushort4*)(sp + base + kk * 4);
        const unsigned ev[4] = {e4.x, e4.y, e4.z, e4.w};

        float s[4]; int idxs[4]; bool oks[4];
#pragma unroll
        for (int sub = 0; sub < 4; ++sub) {
            const int kpos = kk * 4 + sub;
            const unsigned e = ev[sub];
            const int iv = (int)(e & 0x7FFu);
            const bool ok = (kpos < nk) && ((e >> (11 + hj)) & 1u);
            idxs[sub] = iv; oks[sub] = ok;
            const float4* kr = (const float4*)(Kh + (size_t)iv * HD);
            float4 k0 = kr[0], k1 = kr[1], k2 = kr[2], k3 = kr[3];
            float da = 0.f, db = 0.f;
            da = fmaf(qg[0].x, k0.x, da); da = fmaf(qg[0].y, k0.y, da);
            da = fmaf(qg[0].z, k0.z, da); da = fmaf(qg[0].w, k0.w, da);
            db = fmaf(qg[1].x, k1.x, db); db = fmaf(qg[1].y, k1.y, db);
            db = fmaf(qg[1].z, k1.z, db); db = fmaf(qg[1].w, k1.w, db);
            da = fmaf(qg[2].x, k2.x, da); da = fmaf(qg[2].y, k2.y, da);
            da = fmaf(qg[2].z, k2.z, da); da = fmaf(qg[2].w, k2.w, da);
            db = fmaf(qg[3].x, k3.x, db); db = fmaf(qg[3].y, k3.y, db);
            db = fmaf(qg[3].z, k3.z, db); db = fmaf(qg[3].w, k3.w, db);
            float dot = da + db;
            dot += __shfl_xor(dot, 1);   // reduce over dg pairs
            dot += __shfl_xor(dot, 2);
            s[sub] = ok ? dot * 0.125f : -INFINITY;
        }

        float cm = fmaxf(fmaxf(s[0], s[1]), fmaxf(s[2], s[3]));
        cm = fmaxf(cm, __shfl_xor(cm, 4));
        cm = fmaxf(cm, __shfl_xor(cm, 8));
        cm = fmaxf(cm, __shfl_xor(cm, 16));
        cm = fmaxf(cm, __shfl_xor(cm, 32));
        const float mn = fmaxf(m, cm);
        if (mn > -INFINITY) {
            const float alpha = expf(m - mn);
            float p[4];
            float ls = 0.f;
#pragma unroll
            for (int sub = 0; sub < 4; ++sub) { p[sub] = expf(s[sub] - mn); ls += p[sub]; }
            // sum over key slots (same-dg subset): each key counted once
            ls += __shfl_xor(ls, 4);
            ls += __shfl_xor(ls, 8);
            ls += __shfl_xor(ls, 16);
            ls += __shfl_xor(ls, 32);
            l = l * alpha + ls;
#pragma unroll
            for (int i = 0; i < 16; ++i) acc[i] *= alpha;
#pragma unroll
            for (int sub = 0; sub < 4; ++sub) {
                if (oks[sub]) {
                    const float pv = p[sub];
                    const float4* vr = (const float4*)(Vh + (size_t)idxs[sub] * HD);
                    float4 v0 = vr[0], v1 = vr[1], v2 = vr[2], v3 = vr[3];
                    acc[0]  = fmaf(pv, v0.x, acc[0]);  acc[1]  = fmaf(pv, v0.y, acc[1]);
                    acc[2]  = fmaf(pv, v0.z, acc[2]);  acc[3]  = fmaf(pv, v0.w, acc[3]);
                    acc[4]  = fmaf(pv, v1.x, acc[4]);  acc[5]  = fmaf(pv, v1.y, acc[5]);
                    acc[6]  = fmaf(pv, v1.z, acc[6]);  acc[7]  = fmaf(pv, v1.w, acc[7]);
                    acc[8]  = fmaf(pv, v2.x, acc[8]);  acc[9]  = fmaf(pv, v2.y, acc[9]);
                    acc[10] = fmaf(pv, v2.z, acc[10]); acc[11] = fmaf(pv, v2.w, acc[11]);
                    acc[12] = fmaf(pv, v3.x, acc[12]); acc[13] = fmaf(pv, v3.y, acc[13]);
                    acc[14] = fmaf(pv, v3.z, acc[14]); acc[15] = fmaf(pv, v3.w, acc[15]);
                }
            }
            m = mn;
        }
    }

    // reduce acc over the 16 key-slot lanes (same dg)
#pragma unroll
    for (int i = 0; i < 16; ++i) {
        acc[i] += __shfl_xor(acc[i], 4);
        acc[i] += __shfl_xor(acc[i], 8);
        acc[i] += __shfl_xor(acc[i], 16);
        acc[i] += __shfl_xor(acc[i], 32);
    }
    const float invl = 1.f / l;
    float oval = acc[0];
#pragma unroll
    for (int i = 1; i < 16; ++i) if (kk == i) oval = acc[i];
    const int d = dg * 16 + kk;
    const float gs = gosep[(size_t)q * C_DIM + h * HD + d];
    ogb[(size_t)q * C_DIM + h * HD + d] = f2bf(oval * invl * gs);
}

extern "C" void kernel_launch(void* const* d_in, const int* in_sizes, int n_in,
                              void* d_out, int out_size, void* d_ws, size_t ws_size,
                              hipStream_t stream)
{
    const float* x   = (const float*)d_in[0];
    const float* WIq = (const float*)d_in[1];
    const float* WIk = (const float*)d_in[2];
    const float* WIw = (const float*)d_in[3];
    const float* gb  = (const float*)d_in[4];
    const float* hib = (const float*)d_in[5];
    const float* Wq  = (const float*)d_in[6];
    const float* Wk  = (const float*)d_in[7];
    const float* Wv  = (const float*)d_in[8];
    const float* Wgv = (const float*)d_in[9];
    const float* Wgo = (const float*)d_in[10];
    const float* Wo  = (const float*)d_in[11];
    float* out = (float*)d_out;

    char* ws = (char*)d_ws;
    const size_t MB = 1024 * 1024;
    float*    qI     = (float*)(ws + 0 * MB);                 // 1 MB
    float*    kI     = (float*)(ws + 1 * MB);                 // 1 MB
    float*    wsig   = (float*)(ws + 2 * MB);                 // 32 KB
    unsigned* cnts   = (unsigned*)(ws + 2 * MB + 64 * 1024);  // 32 KB
    float*    cost   = (float*)(ws + 2 * MB + 512 * 1024);    // 256 KB
    float*    sint   = (float*)(ws + 2 * MB + 768 * 1024);    // 256 KB
    float*    gosep  = (float*)(ws + 3 * MB);                 // 8 MB  -> 11
    float*    Q      = (float*)(ws + 11 * MB);                // 8 MB  -> 19
    float*    K      = (float*)(ws + 19 * MB);                // 8 MB  -> 27
    float*    V      = (float*)(ws + 27 * MB);                // 8 MB  -> 35
    unsigned short* sidx = (unsigned short*)(ws + 35 * MB);   // 16 MB -> 51
    // region A (51..91): qik partials (16) -> imp (32, 2 hi at a time) -> lincat (40)
    float*    part   = (float*)(ws + 51 * MB);
    float*    imp    = (float*)(ws + 51 * MB);
    float*    lincat = (float*)(ws + 51 * MB);
    unsigned short* ogb   = (unsigned short*)(ws + 91 * MB);  // 4 MB  -> 95
    unsigned short* xb    = (unsigned short*)(ws + 95 * MB);  // 4 MB  -> 99
    unsigned short* Wcatb = (unsigned short*)(ws + 99 * MB);  // 10 MB -> 109
    unsigned short* Wob   = (unsigned short*)(ws + 109 * MB); // 2 MB  -> 111

    rope_table_kernel<<<dim3(256), 256, 0, stream>>>(cost, sint);
    qik_splitk_kernel<<<dim3(2, 8, 16), 256, 0, stream>>>(x, WIq, WIk, part);
    qik_reduce_kernel<<<dim3(2048), 256, 0, stream>>>(part, qI, kI);
    proj_w_kernel<<<dim3(128), 256, 0, stream>>>(x, WIw, wsig);
    for (int h2 = 0; h2 < 2; ++h2) {
        impA_kernel<<<dim3(136, 2), 256, 0, stream>>>(qI, kI, wsig, gb, imp, h2 * 2);
        impB_kernel<<<dim3(512, 2), 256, 0, stream>>>(imp, hib, sidx, cnts, h2 * 2);
    }
    convert_all_kernel<<<dim3(8192), 256, 0, stream>>>(
        x, Wq, Wk, Wv, Wgv, Wgo, Wo, xb, Wcatb, Wob);
    gemm_bf16_kernel<<<dim3(40, 16), 256, 0, stream>>>(xb, Wcatb, lincat, NCAT);
    rope_v_kernel<<<dim3(4096), 256, 0, stream>>>(lincat, cost, sint, Q, K, V, gosep);
    attn_sparse_kernel<<<dim3(512, 16), 256, 0, stream>>>(Q, K, V, sidx, cnts, gosep, ogb);
    gemm_bf16_kernel<<<dim3(8, 16), 256, 0, stream>>>(ogb, Wob, out, C_DIM);
}